// Round 9
// baseline (174.803 us; speedup 1.0000x reference)
//
#include <hip/hip_runtime.h>
#include <cmath>

#define NUMB 21
#define HW (512*512)
#define OUTC 66   // 3*(NUM+1)

using short8 = __attribute__((ext_vector_type(8))) short;
using f32x4  = __attribute__((ext_vector_type(4))) float;

// ---- d_ws layout (uint4 units) ----
// [0, 12288)            fp32 weights (194568 B used)
// [12288, 211200)       packed B fragments (768*259 u4)
// [211200, 681600)      padded bf16 image 12 x 560 x 560
#define WSB4 12288u
#define PIMG_U4 211200u
#define WS_MID 3379200u        // bytes: weights + packed B
#define WS_NEEDED 10905600u    // bytes: + padded image

struct KPtrs { const float* k[NUMB]; };

__device__ __forceinline__ unsigned short f2bf(float f) {
  unsigned u = __builtin_bit_cast(unsigned, f);
  unsigned r = (u + 0x7fffu + ((u >> 16) & 1u)) >> 16;
  return (unsigned short)r;
}

__device__ __forceinline__ void nt_store4(const f32x4 v, float* p) {
  __builtin_nontemporal_store(v, (f32x4*)p);
}

// ---------------- weight construction + softmax (fp32, all 21 blurs) ----------------
__global__ __launch_bounds__(256) void weights_kernel(KPtrs kp, float* __restrict__ w) {
  const int bid = blockIdx.x;
  const int i = bid / 3, c = bid - 3 * (bid / 3);
  const int p = i + 1, s = 2 * p + 1, q = p + 1;
  int off = 0;
  for (int j = 0; j < i; ++j) { const int sj = 3 + 2 * j; off += 3 * sj * sj; }
  float* __restrict__ wd = w + off + c * s * s;
  const float* __restrict__ kc = kp.k[i] + c * q * q;
  const int n = s * s;
  const int tid = threadIdx.x;
  __shared__ float red[256];

  float m = -1e30f;
  for (int idx = tid; idx < n; idx += 256) {
    const int my = idx / s, nx = idx - my * s;
    const int a = min(my, 2 * p - my), bq = min(nx, 2 * p - nx);
    m = fmaxf(m, kc[a * q + bq] + kc[bq * q + a]);
  }
  red[tid] = m; __syncthreads();
  for (int st = 128; st > 0; st >>= 1) {
    if (tid < st) red[tid] = fmaxf(red[tid], red[tid + st]);
    __syncthreads();
  }
  const float vmax = red[0];
  __syncthreads();

  float sum = 0.f;
  for (int idx = tid; idx < n; idx += 256) {
    const int my = idx / s, nx = idx - my * s;
    const int a = min(my, 2 * p - my), bq = min(nx, 2 * p - nx);
    sum += expf(kc[a * q + bq] + kc[bq * q + a] - vmax);
  }
  red[tid] = sum; __syncthreads();
  for (int st = 128; st > 0; st >>= 1) {
    if (tid < st) red[tid] += red[tid + st];
    __syncthreads();
  }
  const float inv = 1.f / red[0];

  for (int idx = tid; idx < n; idx += 256) {
    const int my = idx / s, nx = idx - my * s;
    const int a = min(my, 2 * p - my), bq = min(nx, 2 * p - nx);
    wd[idx] = expf(kc[a * q + bq] + kc[bq * q + a] - vmax) * inv;
  }
}

// ---------------- pack B fragments: 5 groups x 4 blurs x 4 phases ----------------
__global__ __launch_bounds__(64) void pack_b2_kernel(const float* __restrict__ w,
                                                     uint4* __restrict__ ws) {
  const int gs = blockIdx.x;            // 0..258 global step
  const int d  = blockIdx.y;            // 0..3
  const int c  = blockIdx.z;            // 0..2
  const int lane = threadIdx.x;
  int I0, CS, sb, ag;
  if (gs < 11)       { I0 = 1;  CS = 1; sb = 0;   ag = 3; }
  else if (gs < 49)  { I0 = 5;  CS = 2; sb = 11;  ag = 7; }
  else if (gs < 103) { I0 = 9;  CS = 2; sb = 49;  ag = 3; }
  else if (gs < 173) { I0 = 13; CS = 2; sb = 103; ag = 7; }
  else               { I0 = 17; CS = 2; sb = 173; ag = 3; }
  const int T = 2 * I0 + 9, PM = I0 + 4, STEPS = T * CS;
  const int ORI = PM + ag;
  const int q = gs - sb;
  const int t  = (CS == 2) ? (q >> 1) : q;
  const int cs = (CS == 2) ? (q & 1) : 0;
  const int n = lane & 15, g4 = lane >> 4;
  const int j = n >> 2, h = n & 3;
  const int i = I0 + j;                 // absolute blur index
  const int p = i + 1, s = 2 * i + 3;
  int off = 0;
  for (int jj2 = 0; jj2 < i; ++jj2) { const int sj = 3 + 2 * jj2; off += 3 * sj * sj; }
  const float* __restrict__ wk = w + off + c * s * s;
  const int ky = t - PM + p;
  unsigned short hs[8];
#pragma unroll
  for (int jj = 0; jj < 8; ++jj) {
    const int k = 32 * cs + 8 * g4 + jj;
    const int kx = k - ORI - 4 * h - d + p;
    float v = 0.f;
    if (ky >= 0 && ky < s && kx >= 0 && kx < s) v = wk[ky * s + kx];
    hs[jj] = f2bf(v);
  }
  uint4 o;
  o.x = (unsigned)hs[0] | ((unsigned)hs[1] << 16);
  o.y = (unsigned)hs[2] | ((unsigned)hs[3] << 16);
  o.z = (unsigned)hs[4] | ((unsigned)hs[5] << 16);
  o.w = (unsigned)hs[6] | ((unsigned)hs[7] << 16);
  ws[(size_t)WSB4 + 768u * (unsigned)sb + (size_t)(((c * 4 + d) * STEPS + q) * 64 + lane)] = o;
}

// ------- fused: padded bf16 image (12x560x560, reflect-24) + identity channels -------
__global__ __launch_bounds__(256) void pad_copy_kernel(const float* __restrict__ x,
                                                       uint4* __restrict__ ws,
                                                       float* __restrict__ out) {
  const int ch = blockIdx.y;                       // 0..11
  const int chunk = blockIdx.x * 256 + threadIdx.x; // 8-elem chunks, 39200 per ch
  if (chunk >= 39200) return;
  const int pr = chunk / 70, pc8 = (chunk - pr * 70) * 8;
  int gy = pr - 24; gy = gy < 0 ? -gy : gy; gy = gy > 511 ? 1022 - gy : gy;
  const float* __restrict__ row = x + (size_t)ch * HW + (size_t)gy * 512;
  unsigned short hs[8];
  if (pc8 >= 24 && pc8 <= 528) {
    const f32x4 v0 = *(const f32x4*)(row + pc8 - 24);
    const f32x4 v1 = *(const f32x4*)(row + pc8 - 20);
    hs[0] = f2bf(v0.x); hs[1] = f2bf(v0.y); hs[2] = f2bf(v0.z); hs[3] = f2bf(v0.w);
    hs[4] = f2bf(v1.x); hs[5] = f2bf(v1.y); hs[6] = f2bf(v1.z); hs[7] = f2bf(v1.w);
    if (pr >= 24 && pr < 536) {   // interior row: emit identity channel copy
      const int b = ch / 3, c = ch - 3 * (ch / 3);
      float* o = out + ((size_t)(b * OUTC + c)) * HW + (size_t)(pr - 24) * 512 + (pc8 - 24);
      nt_store4(v0, o); nt_store4(v1, o + 4);
    }
  } else {
#pragma unroll
    for (int j = 0; j < 8; ++j) {
      int gx = pc8 + j - 24; gx = gx < 0 ? -gx : gx; gx = gx > 511 ? 1022 - gx : gx;
      hs[j] = f2bf(row[gx]);
    }
  }
  uint4 o;
  o.x = (unsigned)hs[0] | ((unsigned)hs[1] << 16);
  o.y = (unsigned)hs[2] | ((unsigned)hs[3] << 16);
  o.z = (unsigned)hs[4] | ((unsigned)hs[5] << 16);
  o.w = (unsigned)hs[6] | ((unsigned)hs[7] << 16);
  ws[(size_t)PIMG_U4 + (size_t)ch * 39200 + chunk] = o;
}

// ---------------- identity channels (fallback paths) ----------------
__global__ __launch_bounds__(256) void copy_x_kernel(const f32x4* __restrict__ x,
                                                     f32x4* __restrict__ out) {
  const int idx = blockIdx.x * 256 + threadIdx.x;
  const int per_b = 3 * HW / 4;
  const int b = idx / per_b, r = idx - b * per_b;
  __builtin_nontemporal_store(x[idx], &out[(size_t)b * (OUTC * HW / 4) + r]);
}

// ---------------- shared MFMA compute + split-store (h-in-LSB ot layout) ----------------
// ot physical: p = (q*4+j)*272 + 68*g4 + 16*d + 4*r + h  <->  logical x = 64g4+16r+4h+d.
// Writer banks: 16(j&1)+4g4+h -> 32 distinct, 2-way = free. Reader gathers stride-16.
template<int I0, int SB>
__device__ __forceinline__ void convg_compute_store(const int tid, const int b_, const int c,
    const int X0, const int Y0, const unsigned short* __restrict__ tile, float* __restrict__ ot,
    const uint4* __restrict__ wsb, float* __restrict__ out) {
  constexpr int T  = 2 * I0 + 9;
  constexpr int CS = (I0 == 1) ? 1 : 2;
  constexpr int C  = (CS == 1) ? 272 : 304;
  constexpr int CH0 = 3 + 3 * I0;
  constexpr int STEPS = T * CS;

  const int lane = tid & 63, d = tid >> 6;       // wave = pixel phase d 0..3
  const int m = lane & 15, g4 = lane >> 4;
  const int abase = 16 * m + 8 * g4;             // A element base
  const uint4* __restrict__ bl = wsb + (size_t)WSB4 + 768u * (unsigned)SB
                               + (size_t)((c * 4 + d) * STEPS) * 64 + lane;

  f32x4 acc[8];
#pragma unroll
  for (int yy = 0; yy < 8; ++yy) acc[yy] = (f32x4){0.f, 0.f, 0.f, 0.f};

  short8 awin[8][CS];
#pragma unroll
  for (int r = 0; r < 7; ++r)
#pragma unroll
    for (int cs2 = 0; cs2 < CS; ++cs2)
      awin[r][cs2] = *(const short8*)(tile + r * C + abase + 32 * cs2);

  short8 Bf[4][CS];                               // ring-4, prefetch distance 3
#pragma unroll
  for (int tt = 0; tt < 3; ++tt)
#pragma unroll
    for (int cs2 = 0; cs2 < CS; ++cs2)
      Bf[tt][cs2] = __builtin_bit_cast(short8, bl[(tt * CS + cs2) * 64]);

#pragma unroll
  for (int t = 0; t < T; ++t) {
#pragma unroll
    for (int cs2 = 0; cs2 < CS; ++cs2)
      awin[(t + 7) & 7][cs2] = *(const short8*)(tile + (t + 7) * C + abase + 32 * cs2);
    if (t + 3 < T) {
#pragma unroll
      for (int cs2 = 0; cs2 < CS; ++cs2)
        Bf[(t + 3) & 3][cs2] = __builtin_bit_cast(short8, bl[((t + 3) * CS + cs2) * 64]);
    }
#pragma unroll
    for (int yy = 0; yy < 8; ++yy)
#pragma unroll
      for (int cs2 = 0; cs2 < CS; ++cs2)
        acc[yy] = __builtin_amdgcn_mfma_f32_16x16x32_bf16(awin[(t + yy) & 7][cs2],
                                                          Bf[t & 3][cs2], acc[yy], 0, 0, 0);
  }

  // ---- coalesced store via LDS transpose, two 4-row halves (ot = 16x272 f32) ----
#pragma unroll
  for (int H = 0; H < 2; ++H) {
    __syncthreads();                             // H=0: done reading tile; H=1: half-0 drained
    {
      const int n = lane & 15;
      const int j = n >> 2, h = n & 3;
#pragma unroll
      for (int q = 0; q < 4; ++q) {
        float* obase_lds = ot + (q * 4 + j) * 272 + 68 * g4 + 16 * d + h;
        const int yy = H * 4 + q;
#pragma unroll
        for (int r = 0; r < 4; ++r) obase_lds[4 * r] = acc[yy][r];
      }
    }
    __syncthreads();
    {
      const int jw = tid >> 6, rem = tid & 63;
      const int yy2l = rem >> 4, kq = rem & 15;
      float* __restrict__ obase = out + ((size_t)(b_ * OUTC + CH0 + 3 * jw + c)) * HW
                                + (size_t)(Y0 + H * 4 + yy2l) * 512 + X0;
      const float* __restrict__ srow = ot + (yy2l * 4 + jw) * 272
                                     + 4 * (kq >> 2) + (kq & 3);
#pragma unroll
      for (int v = 0; v < 4; ++v) {
        const float* sv = srow + 68 * v;
        f32x4 val = (f32x4){sv[0], sv[16], sv[32], sv[48]};
        nt_store4(val, obase + 64 * v + 4 * kq);
      }
    }
  }
}

// ---------------- merged MFMA conv: global_load_lds staging from padded bf16 image ----------------
template<int I0, int SB>
__device__ __forceinline__ void convg_body(const int lbid,
    const unsigned short* __restrict__ pimg, const uint4* __restrict__ wsb,
    float* __restrict__ out, char* smem) {
  constexpr int T  = 2 * I0 + 9;
  constexpr int CS = (I0 == 1) ? 1 : 2;
  constexpr int PM = I0 + 4;
  constexpr int AG = (8 - (PM & 7)) & 7;
  constexpr int ORI = PM + AG;
  constexpr int RT = T + 7;
  constexpr int C  = (CS == 1) ? 272 : 304;
  constexpr int CW8 = C / 8;
  constexpr int NIDX = RT * CW8;
  static_assert(NIDX * 16 <= 32768, "tile overflow");

  unsigned short* tile = (unsigned short*)smem;
  float* ot = (float*)smem;
  const int tid = threadIdx.x;
  const int bx = lbid & 1, by = (lbid >> 1) & 63, bz = lbid >> 7;
  const int b_ = bz / 3, c = bz - b_ * 3;
  const int X0 = bx * 256, Y0 = by * 8;

  const unsigned short* __restrict__ pb = pimg + (size_t)(b_ * 3 + c) * 313600
        + (size_t)(Y0 - PM + 24) * 560 + (X0 - ORI + 24);
  {
    const int wid = tid >> 6, lane = tid & 63;
    for (int base = wid * 64; base < NIDX; base += 256) {
      const int idx = base + lane;
      const int r = idx / CW8, cc = idx - r * CW8;
      const unsigned short* src = pb + r * 560 + cc * 8;
      unsigned short* dst = tile + (size_t)base * 8;   // wave-uniform; HW appends lane*16B
      if (idx < NIDX)
        __builtin_amdgcn_global_load_lds(
            (const __attribute__((address_space(1))) void*)src,
            (__attribute__((address_space(3))) void*)dst, 16, 0, 0);
    }
  }
  __syncthreads();
  convg_compute_store<I0, SB>(tid, b_, c, X0, Y0, tile, ot, wsb, out);
}

__global__ __launch_bounds__(256, 4) void convg_all_kernel(
    const unsigned short* __restrict__ pimg, const uint4* __restrict__ wsb,
    float* __restrict__ out) {
  __shared__ __align__(16) char smem[32768];
  const int gi = blockIdx.x;
  // group-local XCD swizzle: each XCD (gi%8) owns 192 contiguous lbids.
  const int grp = gi / 1536;
  const int lb = gi - grp * 1536;
  const int lbid = (lb & 7) * 192 + (lb >> 3);
  if (grp == 0)      convg_body<17, 173>(lbid, pimg, wsb, out, smem);
  else if (grp == 1) convg_body<13, 103>(lbid, pimg, wsb, out, smem);
  else if (grp == 2) convg_body<9,  49 >(lbid, pimg, wsb, out, smem);
  else if (grp == 3) convg_body<5,  11 >(lbid, pimg, wsb, out, smem);
  else               convg_body<1,  0  >(lbid, pimg, wsb, out, smem);
}

// ---------------- per-group MFMA conv, scalar staging (mid-ws fallback) ----------------
template<int I0, int SB>
__global__ __launch_bounds__(256, 3) void convg_kernel(const float* __restrict__ xall,
                                                       const uint4* __restrict__ wsb,
                                                       float* __restrict__ out) {
  constexpr int T  = 2 * I0 + 9;
  constexpr int PM = I0 + 4;
  constexpr int AG = (8 - (PM & 7)) & 7;
  constexpr int ORI = PM + AG;
  constexpr int RT = T + 7;
  constexpr int CS = (I0 == 1) ? 1 : 2;
  constexpr int C  = (CS == 1) ? 272 : 304;

  __shared__ __align__(16) char smem[32768];
  unsigned short* tile = (unsigned short*)smem;
  float* ot = (float*)smem;

  const int tid = threadIdx.x;
  const int b_ = blockIdx.z / 3, c = blockIdx.z - b_ * 3;
  const int X0 = blockIdx.x * 256, Y0 = blockIdx.y * 8;
  const float* __restrict__ xin = xall + (size_t)(b_ * 3 + c) * HW;

  for (int idx = tid; idx < RT * C; idx += 256) {
    const int r = idx / C, e = idx - r * C;
    int gy = Y0 - PM + r; gy = gy < 0 ? -gy : gy; gy = gy > 511 ? 1022 - gy : gy;
    int gx = X0 - ORI + e; gx = gx < 0 ? -gx : gx; gx = gx > 511 ? 1022 - gx : gx;
    tile[idx] = f2bf(xin[gy * 512 + gx]);
  }
  __syncthreads();
  convg_compute_store<I0, SB>(tid, b_, c, X0, Y0, tile, ot, wsb, out);
}

// ---------------- fp32 depthwise conv (blur 0 / full fallback) ----------------
template<int S>
__global__ __launch_bounds__(256) void conv_kernel(const float* __restrict__ xin_all,
                                                   const float* __restrict__ wg,
                                                   float* __restrict__ out, int ch0) {
  constexpr int P = (S - 1) / 2;
  constexpr int WHALO = 128 + 2 * P;
  constexpr int STRIDE = (WHALO + 3) & ~3;
  constexpr int HHALO = 32 + 2 * P;
  constexpr int NSEG = (S + 6) / 4;
  extern __shared__ float lds[];

  const int tx = threadIdx.x, ty = threadIdx.y;
  const int bz = blockIdx.z;
  const int b = bz / 3, c = bz - 3 * (bz / 3);
  const int x0 = blockIdx.x * 128, y0 = blockIdx.y * 32;
  const float* __restrict__ xin = xin_all + ((size_t)(b * 3 + c)) * HW;
  const float* __restrict__ wb = wg + c * (S * S);

  for (int ly = ty; ly < HHALO; ly += 8) {
    int gy = y0 - P + ly;
    gy = gy < 0 ? -gy : gy;
    gy = gy > 511 ? 1022 - gy : gy;
    const float* __restrict__ row = xin + (size_t)gy * 512;
    for (int lx = tx; lx < WHALO; lx += 32) {
      int gx = x0 - P + lx;
      gx = gx < 0 ? -gx : gx;
      gx = gx > 511 ? 1022 - gx : gx;
      lds[ly * STRIDE + lx] = row[gx];
    }
  }
  __syncthreads();

  float acc[4][4] = {};
  const int basecol = tx * 4;
  const int lrow0 = ty * 4;

#pragma unroll 1
  for (int ri = 0; ri < S + 3; ++ri) {
    float seg[NSEG * 4];
    const float* lp = &lds[(lrow0 + ri) * STRIDE + basecol];
#pragma unroll
    for (int j2 = 0; j2 < NSEG; ++j2) {
      const float4 v = *(const float4*)(lp + 4 * j2);
      seg[4 * j2 + 0] = v.x; seg[4 * j2 + 1] = v.y;
      seg[4 * j2 + 2] = v.z; seg[4 * j2 + 3] = v.w;
    }
#pragma unroll
    for (int r = 0; r < 4; ++r) {
      const int dy = ri - r;
      if (dy >= 0 && dy < S) {
        const float* __restrict__ wrow = wb + dy * S;
#pragma unroll
        for (int dx = 0; dx < S; ++dx) {
          const float wv = wrow[dx];
#pragma unroll
          for (int cc = 0; cc < 4; ++cc)
            acc[r][cc] = fmaf(wv, seg[dx + cc], acc[r][cc]);
        }
      }
    }
  }

  float* __restrict__ o = out + ((size_t)b * OUTC + (ch0 + c)) * HW
                        + (size_t)(y0 + lrow0) * 512 + (x0 + basecol);
#pragma unroll
  for (int r = 0; r < 4; ++r) {
    f32x4 v = (f32x4){acc[r][0], acc[r][1], acc[r][2], acc[r][3]};
    nt_store4(v, o + (size_t)r * 512);
  }
}

extern "C" void kernel_launch(void* const* d_in, const int* in_sizes, int n_in,
                              void* d_out, int out_size, void* d_ws, size_t ws_size,
                              hipStream_t stream) {
  (void)in_sizes; (void)n_in; (void)out_size;
  const float* x = (const float*)d_in[0];
  float* out = (float*)d_out;
  float* w = (float*)d_ws;

  KPtrs kp;
  for (int i = 0; i < NUMB; ++i) kp.k[i] = (const float*)d_in[1 + i];

  weights_kernel<<<dim3(63), dim3(256), 0, stream>>>(kp, w);

  int offs[NUMB];
  { int off = 0; for (int i = 0; i < NUMB; ++i) { offs[i] = off; const int s = 3 + 2 * i; off += 3 * s * s; } }

#define LAUNCH_CONV(I) do { \
    constexpr int S_ = 3 + 2 * (I); \
    constexpr int P_ = (I) + 1; \
    constexpr int STRIDE_ = ((128 + 2 * P_) + 3) & ~3; \
    constexpr int HHALO_ = 32 + 2 * P_; \
    conv_kernel<S_><<<dim3(4, 16, 12), dim3(32, 8), (size_t)STRIDE_ * HHALO_ * sizeof(float), stream>>>( \
        x, w + offs[I], out, 3 + 3 * (I)); \
  } while (0)

  // blur 0 (3x3) on the fp32 path
  LAUNCH_CONV(0);

  if (ws_size >= WS_NEEDED) {
    pad_copy_kernel<<<dim3(154, 12), dim3(256), 0, stream>>>(x, (uint4*)d_ws, out);
    pack_b2_kernel<<<dim3(259, 4, 3), dim3(64), 0, stream>>>(w, (uint4*)d_ws);
    const unsigned short* pimg = (const unsigned short*)((const uint4*)d_ws + PIMG_U4);
    convg_all_kernel<<<dim3(7680), dim3(256), 0, stream>>>(pimg, (const uint4*)d_ws, out);
  } else if (ws_size >= WS_MID) {
    copy_x_kernel<<<dim3(3072), dim3(256), 0, stream>>>((const f32x4*)x, (f32x4*)out);
    pack_b2_kernel<<<dim3(259, 4, 3), dim3(64), 0, stream>>>(w, (uint4*)d_ws);
    convg_kernel<17, 173><<<dim3(2, 64, 12), dim3(256), 0, stream>>>(x, (const uint4*)d_ws, out);
    convg_kernel<13, 103><<<dim3(2, 64, 12), dim3(256), 0, stream>>>(x, (const uint4*)d_ws, out);
    convg_kernel<9,  49 ><<<dim3(2, 64, 12), dim3(256), 0, stream>>>(x, (const uint4*)d_ws, out);
    convg_kernel<5,  11 ><<<dim3(2, 64, 12), dim3(256), 0, stream>>>(x, (const uint4*)d_ws, out);
    convg_kernel<1,  0  ><<<dim3(2, 64, 12), dim3(256), 0, stream>>>(x, (const uint4*)d_ws, out);
  } else {
    copy_x_kernel<<<dim3(3072), dim3(256), 0, stream>>>((const f32x4*)x, (f32x4*)out);
    LAUNCH_CONV(1);  LAUNCH_CONV(2);  LAUNCH_CONV(3);  LAUNCH_CONV(4);
    LAUNCH_CONV(5);  LAUNCH_CONV(6);  LAUNCH_CONV(7);  LAUNCH_CONV(8);
    LAUNCH_CONV(9);  LAUNCH_CONV(10); LAUNCH_CONV(11); LAUNCH_CONV(12);
    LAUNCH_CONV(13); LAUNCH_CONV(14); LAUNCH_CONV(15); LAUNCH_CONV(16);
    LAUNCH_CONV(17); LAUNCH_CONV(18); LAUNCH_CONV(19); LAUNCH_CONV(20);
  }
#undef LAUNCH_CONV
}

// Round 10
// 171.275 us; speedup vs baseline: 1.0206x; 1.0206x over previous
//
#include <hip/hip_runtime.h>
#include <cmath>

#define NUMB 21
#define HW (512*512)
#define OUTC 66   // 3*(NUM+1)

using short8 = __attribute__((ext_vector_type(8))) short;
using f32x4  = __attribute__((ext_vector_type(4))) float;

// ---- d_ws layout (uint4 units) ----
// [0, 12288)            fp32 weights (194568 B used)
// [12288, 211200)       packed B fragments (768*259 u4)
// [211200, 681600)      padded bf16 image 12 x 560 x 560
#define WSB4 12288u
#define PIMG_U4 211200u
#define WS_MID 3379200u        // bytes: weights + packed B
#define WS_NEEDED 10905600u    // bytes: + padded image

struct KPtrs { const float* k[NUMB]; };

__device__ __forceinline__ unsigned short f2bf(float f) {
  unsigned u = __builtin_bit_cast(unsigned, f);
  unsigned r = (u + 0x7fffu + ((u >> 16) & 1u)) >> 16;
  return (unsigned short)r;
}

__device__ __forceinline__ void nt_store4(const f32x4 v, float* p) {
  __builtin_nontemporal_store(v, (f32x4*)p);
}

// ---------------- device bodies shared by fused + standalone kernels ----------------

__device__ __forceinline__ void weights_body(const int bid, const int tid,
                                             const KPtrs& kp, float* __restrict__ w,
                                             float* red) {
  const int i = bid / 3, c = bid - 3 * (bid / 3);
  const int p = i + 1, s = 2 * p + 1, q = p + 1;
  int off = 0;
  for (int j = 0; j < i; ++j) { const int sj = 3 + 2 * j; off += 3 * sj * sj; }
  float* __restrict__ wd = w + off + c * s * s;
  const float* __restrict__ kc = kp.k[i] + c * q * q;
  const int n = s * s;

  float m = -1e30f;
  for (int idx = tid; idx < n; idx += 256) {
    const int my = idx / s, nx = idx - my * s;
    const int a = min(my, 2 * p - my), bq = min(nx, 2 * p - nx);
    m = fmaxf(m, kc[a * q + bq] + kc[bq * q + a]);
  }
  red[tid] = m; __syncthreads();
  for (int st = 128; st > 0; st >>= 1) {
    if (tid < st) red[tid] = fmaxf(red[tid], red[tid + st]);
    __syncthreads();
  }
  const float vmax = red[0];
  __syncthreads();

  float sum = 0.f;
  for (int idx = tid; idx < n; idx += 256) {
    const int my = idx / s, nx = idx - my * s;
    const int a = min(my, 2 * p - my), bq = min(nx, 2 * p - nx);
    sum += expf(kc[a * q + bq] + kc[bq * q + a] - vmax);
  }
  red[tid] = sum; __syncthreads();
  for (int st = 128; st > 0; st >>= 1) {
    if (tid < st) red[tid] += red[tid + st];
    __syncthreads();
  }
  const float inv = 1.f / red[0];

  for (int idx = tid; idx < n; idx += 256) {
    const int my = idx / s, nx = idx - my * s;
    const int a = min(my, 2 * p - my), bq = min(nx, 2 * p - nx);
    wd[idx] = expf(kc[a * q + bq] + kc[bq * q + a] - vmax) * inv;
  }
}

__device__ __forceinline__ void pad_copy_body(const int ch, const int chunk,
                                              const float* __restrict__ x,
                                              uint4* __restrict__ ws,
                                              float* __restrict__ out) {
  if (chunk >= 39200) return;
  const int pr = chunk / 70, pc8 = (chunk - pr * 70) * 8;
  int gy = pr - 24; gy = gy < 0 ? -gy : gy; gy = gy > 511 ? 1022 - gy : gy;
  const float* __restrict__ row = x + (size_t)ch * HW + (size_t)gy * 512;
  unsigned short hs[8];
  if (pc8 >= 24 && pc8 <= 528) {
    const f32x4 v0 = *(const f32x4*)(row + pc8 - 24);
    const f32x4 v1 = *(const f32x4*)(row + pc8 - 20);
    hs[0] = f2bf(v0.x); hs[1] = f2bf(v0.y); hs[2] = f2bf(v0.z); hs[3] = f2bf(v0.w);
    hs[4] = f2bf(v1.x); hs[5] = f2bf(v1.y); hs[6] = f2bf(v1.z); hs[7] = f2bf(v1.w);
    if (pr >= 24 && pr < 536) {   // interior row: emit identity channel copy
      const int b = ch / 3, c = ch - 3 * (ch / 3);
      float* o = out + ((size_t)(b * OUTC + c)) * HW + (size_t)(pr - 24) * 512 + (pc8 - 24);
      nt_store4(v0, o); nt_store4(v1, o + 4);
    }
  } else {
#pragma unroll
    for (int j = 0; j < 8; ++j) {
      int gx = pc8 + j - 24; gx = gx < 0 ? -gx : gx; gx = gx > 511 ? 1022 - gx : gx;
      hs[j] = f2bf(row[gx]);
    }
  }
  uint4 o;
  o.x = (unsigned)hs[0] | ((unsigned)hs[1] << 16);
  o.y = (unsigned)hs[2] | ((unsigned)hs[3] << 16);
  o.z = (unsigned)hs[4] | ((unsigned)hs[5] << 16);
  o.w = (unsigned)hs[6] | ((unsigned)hs[7] << 16);
  ws[(size_t)PIMG_U4 + (size_t)ch * 39200 + chunk] = o;
}

__device__ __forceinline__ void pack_b2_body(const int gs, const int d, const int c,
                                             const int lane, const float* __restrict__ w,
                                             uint4* __restrict__ ws) {
  int I0, CS, sb, ag;
  if (gs < 11)       { I0 = 1;  CS = 1; sb = 0;   ag = 3; }
  else if (gs < 49)  { I0 = 5;  CS = 2; sb = 11;  ag = 7; }
  else if (gs < 103) { I0 = 9;  CS = 2; sb = 49;  ag = 3; }
  else if (gs < 173) { I0 = 13; CS = 2; sb = 103; ag = 7; }
  else               { I0 = 17; CS = 2; sb = 173; ag = 3; }
  const int T = 2 * I0 + 9, PM = I0 + 4, STEPS = T * CS;
  const int ORI = PM + ag;
  const int q = gs - sb;
  const int t  = (CS == 2) ? (q >> 1) : q;
  const int cs = (CS == 2) ? (q & 1) : 0;
  const int n = lane & 15, g4 = lane >> 4;
  const int j = n >> 2, h = n & 3;
  const int i = I0 + j;                 // absolute blur index
  const int p = i + 1, s = 2 * i + 3;
  int off = 0;
  for (int jj2 = 0; jj2 < i; ++jj2) { const int sj = 3 + 2 * jj2; off += 3 * sj * sj; }
  const float* __restrict__ wk = w + off + c * s * s;
  const int ky = t - PM + p;
  unsigned short hs[8];
#pragma unroll
  for (int jj = 0; jj < 8; ++jj) {
    const int k = 32 * cs + 8 * g4 + jj;
    const int kx = k - ORI - 4 * h - d + p;
    float v = 0.f;
    if (ky >= 0 && ky < s && kx >= 0 && kx < s) v = wk[ky * s + kx];
    hs[jj] = f2bf(v);
  }
  uint4 o;
  o.x = (unsigned)hs[0] | ((unsigned)hs[1] << 16);
  o.y = (unsigned)hs[2] | ((unsigned)hs[3] << 16);
  o.z = (unsigned)hs[4] | ((unsigned)hs[5] << 16);
  o.w = (unsigned)hs[6] | ((unsigned)hs[7] << 16);
  ws[(size_t)WSB4 + 768u * (unsigned)sb + (size_t)(((c * 4 + d) * STEPS + q) * 64 + lane)] = o;
}

// conv3 (blur 0, S=3) body; lds must be >= 34*132 floats
__device__ __forceinline__ void conv3_body(const int tid, const int bx, const int by, const int bz,
                                           const float* __restrict__ xin_all,
                                           const float* __restrict__ wg,
                                           float* __restrict__ out, float* lds) {
  constexpr int S = 3, P = 1;
  constexpr int WHALO = 130, STRIDE = 132, HHALO = 34, NSEG = 2;
  const int tx = tid & 31, ty = tid >> 5;
  const int b = bz / 3, c = bz - 3 * (bz / 3);
  const int x0 = bx * 128, y0 = by * 32;
  const float* __restrict__ xin = xin_all + ((size_t)(b * 3 + c)) * HW;
  const float* __restrict__ wb = wg + c * (S * S);

  for (int ly = ty; ly < HHALO; ly += 8) {
    int gy = y0 - P + ly;
    gy = gy < 0 ? -gy : gy;
    gy = gy > 511 ? 1022 - gy : gy;
    const float* __restrict__ row = xin + (size_t)gy * 512;
    for (int lx = tx; lx < WHALO; lx += 32) {
      int gx = x0 - P + lx;
      gx = gx < 0 ? -gx : gx;
      gx = gx > 511 ? 1022 - gx : gx;
      lds[ly * STRIDE + lx] = row[gx];
    }
  }
  __syncthreads();

  float acc[4][4] = {};
  const int basecol = tx * 4;
  const int lrow0 = ty * 4;

#pragma unroll 1
  for (int ri = 0; ri < S + 3; ++ri) {
    float seg[NSEG * 4];
    const float* lp = &lds[(lrow0 + ri) * STRIDE + basecol];
#pragma unroll
    for (int j2 = 0; j2 < NSEG; ++j2) {
      const float4 v = *(const float4*)(lp + 4 * j2);
      seg[4 * j2 + 0] = v.x; seg[4 * j2 + 1] = v.y;
      seg[4 * j2 + 2] = v.z; seg[4 * j2 + 3] = v.w;
    }
#pragma unroll
    for (int r = 0; r < 4; ++r) {
      const int dy = ri - r;
      if (dy >= 0 && dy < S) {
        const float* __restrict__ wrow = wb + dy * S;
#pragma unroll
        for (int dx = 0; dx < S; ++dx) {
          const float wv = wrow[dx];
#pragma unroll
          for (int cc = 0; cc < 4; ++cc)
            acc[r][cc] = fmaf(wv, seg[dx + cc], acc[r][cc]);
        }
      }
    }
  }

  float* __restrict__ o = out + ((size_t)b * OUTC + (3 + c)) * HW
                        + (size_t)(y0 + lrow0) * 512 + (x0 + basecol);
#pragma unroll
  for (int r = 0; r < 4; ++r) {
    f32x4 v = (f32x4){acc[r][0], acc[r][1], acc[r][2], acc[r][3]};
    nt_store4(v, o + (size_t)r * 512);
  }
}

// ---------------- fused prep1: pad_copy (1848 blocks) + weights (63 blocks) ----------------
__global__ __launch_bounds__(256) void prep1_kernel(const float* __restrict__ x,
                                                    uint4* __restrict__ ws,
                                                    float* __restrict__ out,
                                                    KPtrs kp, float* __restrict__ w) {
  __shared__ float red[256];
  const int bid = blockIdx.x, tid = threadIdx.x;
  if (bid < 1848) {
    const int ch = bid / 154, cb = bid - ch * 154;
    pad_copy_body(ch, cb * 256 + tid, x, ws, out);
  } else {
    weights_body(bid - 1848, tid, kp, w, red);
  }
}

// ---------------- fused prep2: conv3/blur0 (768 blocks) + pack_b2 (777 blocks x 4 waves) ----------------
__global__ __launch_bounds__(256) void prep2_kernel(const float* __restrict__ x,
                                                    const float* __restrict__ w,
                                                    uint4* __restrict__ ws,
                                                    float* __restrict__ out) {
  __shared__ __align__(16) float lds3[34 * 132];
  const int bid = blockIdx.x, tid = threadIdx.x;
  if (bid < 768) {
    conv3_body(tid, bid & 3, (bid >> 2) & 15, bid >> 6, x, w, out, lds3);
  } else {
    const int u = (bid - 768) * 4 + (tid >> 6);   // 3108 pack units
    const int lane = tid & 63;
    const int gs = u % 259, t2 = u / 259;
    const int d = t2 & 3, c = t2 >> 2;
    pack_b2_body(gs, d, c, lane, w, ws);
  }
}

// ---------------- standalone kernels (fallback paths) ----------------
__global__ __launch_bounds__(256) void weights_kernel(KPtrs kp, float* __restrict__ w) {
  __shared__ float red[256];
  weights_body(blockIdx.x, threadIdx.x, kp, w, red);
}

__global__ __launch_bounds__(64) void pack_b2_kernel(const float* __restrict__ w,
                                                     uint4* __restrict__ ws) {
  pack_b2_body(blockIdx.x, blockIdx.y, blockIdx.z, threadIdx.x, w, ws);
}

__global__ __launch_bounds__(256) void copy_x_kernel(const f32x4* __restrict__ x,
                                                     f32x4* __restrict__ out) {
  const int idx = blockIdx.x * 256 + threadIdx.x;
  const int per_b = 3 * HW / 4;
  const int b = idx / per_b, r = idx - b * per_b;
  __builtin_nontemporal_store(x[idx], &out[(size_t)b * (OUTC * HW / 4) + r]);
}

// ---------------- shared MFMA compute + split-store (round-8 epilogue) ----------------
template<int I0, int SB>
__device__ __forceinline__ void convg_compute_store(const int tid, const int b_, const int c,
    const int X0, const int Y0, const unsigned short* __restrict__ tile, float* __restrict__ ot,
    const uint4* __restrict__ wsb, float* __restrict__ out) {
  constexpr int T  = 2 * I0 + 9;
  constexpr int CS = (I0 == 1) ? 1 : 2;
  constexpr int C  = (CS == 1) ? 272 : 304;
  constexpr int CH0 = 3 + 3 * I0;
  constexpr int STEPS = T * CS;

  const int lane = tid & 63, d = tid >> 6;       // wave = pixel phase d 0..3
  const int m = lane & 15, g4 = lane >> 4;
  const int abase = 16 * m + 8 * g4;             // A element base
  const uint4* __restrict__ bl = wsb + (size_t)WSB4 + 768u * (unsigned)SB
                               + (size_t)((c * 4 + d) * STEPS) * 64 + lane;

  f32x4 acc[8];
#pragma unroll
  for (int yy = 0; yy < 8; ++yy) acc[yy] = (f32x4){0.f, 0.f, 0.f, 0.f};

  short8 awin[8][CS];
#pragma unroll
  for (int r = 0; r < 7; ++r)
#pragma unroll
    for (int cs2 = 0; cs2 < CS; ++cs2)
      awin[r][cs2] = *(const short8*)(tile + r * C + abase + 32 * cs2);

  short8 Bf[4][CS];                               // ring-4, prefetch distance 3
#pragma unroll
  for (int tt = 0; tt < 3; ++tt)
#pragma unroll
    for (int cs2 = 0; cs2 < CS; ++cs2)
      Bf[tt][cs2] = __builtin_bit_cast(short8, bl[(tt * CS + cs2) * 64]);

#pragma unroll
  for (int t = 0; t < T; ++t) {
#pragma unroll
    for (int cs2 = 0; cs2 < CS; ++cs2)
      awin[(t + 7) & 7][cs2] = *(const short8*)(tile + (t + 7) * C + abase + 32 * cs2);
    if (t + 3 < T) {
#pragma unroll
      for (int cs2 = 0; cs2 < CS; ++cs2)
        Bf[(t + 3) & 3][cs2] = __builtin_bit_cast(short8, bl[((t + 3) * CS + cs2) * 64]);
    }
#pragma unroll
    for (int yy = 0; yy < 8; ++yy)
#pragma unroll
      for (int cs2 = 0; cs2 < CS; ++cs2)
        acc[yy] = __builtin_amdgcn_mfma_f32_16x16x32_bf16(awin[(t + yy) & 7][cs2],
                                                          Bf[t & 3][cs2], acc[yy], 0, 0, 0);
  }

  // ---- coalesced store via LDS transpose, two 4-row halves ----
  // Bank note: scatter write is d-pinned (bank%4 == d) -> 8-way floor. Reach it by
  // flipping r's bit per odd g4 (chunk ^= 4*(g4&1)); reader un-permutes on the
  // GLOBAL side (within-256B float4 shuffle, still coalesced), LDS reads stay linear.
  const int rx = g4 & 1;
#pragma unroll
  for (int H = 0; H < 2; ++H) {
    __syncthreads();                             // H=0: done reading tile; H=1: half-0 drained
    {
      const int n = lane & 15;
      const int j = n >> 2, h = n & 3;
#pragma unroll
      for (int q = 0; q < 4; ++q) {
        float* orow = ot + (q * 4 + j) * 260 + 64 * g4 + 4 * h + d;
        const int yy = H * 4 + q;
#pragma unroll
        for (int r = 0; r < 4; ++r) orow[16 * (r ^ rx)] = acc[yy][r];
      }
    }
    __syncthreads();
    {
      const int jw = tid >> 6, rem = tid & 63;
      const int yy2l = rem >> 4, xq2 = rem & 15;
      float* __restrict__ obase = out + ((size_t)(b_ * OUTC + CH0 + 3 * jw + c)) * HW
                                + (size_t)(Y0 + H * 4 + yy2l) * 512 + X0;
      const float* __restrict__ srow = ot + (yy2l * 4 + jw) * 260;
#pragma unroll
      for (int v = 0; v < 4; ++v) {
        const int lofs = v * 64 + 4 * xq2;                    // physical LDS chunk
        const int gofs = v * 64 + 4 * (xq2 ^ (4 * (v & 1))); // logical/global chunk
        nt_store4(*(const f32x4*)(srow + lofs), obase + gofs);
      }
    }
  }
}

// ---------------- merged MFMA conv: global_load_lds staging from padded bf16 image ----------------
template<int I0, int SB>
__device__ __forceinline__ void convg_body(const int lbid,
    const unsigned short* __restrict__ pimg, const uint4* __restrict__ wsb,
    float* __restrict__ out, char* smem) {
  constexpr int T  = 2 * I0 + 9;
  constexpr int CS = (I0 == 1) ? 1 : 2;
  constexpr int PM = I0 + 4;
  constexpr int AG = (8 - (PM & 7)) & 7;
  constexpr int ORI = PM + AG;
  constexpr int RT = T + 7;
  constexpr int C  = (CS == 1) ? 272 : 304;
  constexpr int CW8 = C / 8;
  constexpr int NIDX = RT * CW8;
  static_assert(NIDX * 16 <= 32768, "tile overflow");

  unsigned short* tile = (unsigned short*)smem;
  float* ot = (float*)smem;
  const int tid = threadIdx.x;
  const int bx = lbid & 1, by = (lbid >> 1) & 63, bz = lbid >> 7;
  const int b_ = bz / 3, c = bz - b_ * 3;
  const int X0 = bx * 256, Y0 = by * 8;

  const unsigned short* __restrict__ pb = pimg + (size_t)(b_ * 3 + c) * 313600
        + (size_t)(Y0 - PM + 24) * 560 + (X0 - ORI + 24);
  {
    const int wid = tid >> 6, lane = tid & 63;
    for (int base = wid * 64; base < NIDX; base += 256) {
      const int idx = base + lane;
      const int r = idx / CW8, cc = idx - r * CW8;
      const unsigned short* src = pb + r * 560 + cc * 8;
      unsigned short* dst = tile + (size_t)base * 8;   // wave-uniform; HW appends lane*16B
      if (idx < NIDX)
        __builtin_amdgcn_global_load_lds(
            (const __attribute__((address_space(1))) void*)src,
            (__attribute__((address_space(3))) void*)dst, 16, 0, 0);
    }
  }
  __syncthreads();
  convg_compute_store<I0, SB>(tid, b_, c, X0, Y0, tile, ot, wsb, out);
}

__global__ __launch_bounds__(256, 4) void convg_all_kernel(
    const unsigned short* __restrict__ pimg, const uint4* __restrict__ wsb,
    float* __restrict__ out) {
  __shared__ __align__(16) char smem[32768];
  const int gi = blockIdx.x;
  // group-local XCD swizzle: each XCD (gi%8) owns 192 contiguous lbids.
  const int grp = gi / 1536;
  const int lb = gi - grp * 1536;
  const int lbid = (lb & 7) * 192 + (lb >> 3);
  if (grp == 0)      convg_body<17, 173>(lbid, pimg, wsb, out, smem);
  else if (grp == 1) convg_body<13, 103>(lbid, pimg, wsb, out, smem);
  else if (grp == 2) convg_body<9,  49 >(lbid, pimg, wsb, out, smem);
  else if (grp == 3) convg_body<5,  11 >(lbid, pimg, wsb, out, smem);
  else               convg_body<1,  0  >(lbid, pimg, wsb, out, smem);
}

// ---------------- per-group MFMA conv, scalar staging (mid-ws fallback) ----------------
template<int I0, int SB>
__global__ __launch_bounds__(256, 3) void convg_kernel(const float* __restrict__ xall,
                                                       const uint4* __restrict__ wsb,
                                                       float* __restrict__ out) {
  constexpr int T  = 2 * I0 + 9;
  constexpr int PM = I0 + 4;
  constexpr int AG = (8 - (PM & 7)) & 7;
  constexpr int ORI = PM + AG;
  constexpr int RT = T + 7;
  constexpr int CS = (I0 == 1) ? 1 : 2;
  constexpr int C  = (CS == 1) ? 272 : 304;

  __shared__ __align__(16) char smem[32768];
  unsigned short* tile = (unsigned short*)smem;
  float* ot = (float*)smem;

  const int tid = threadIdx.x;
  const int b_ = blockIdx.z / 3, c = blockIdx.z - b_ * 3;
  const int X0 = blockIdx.x * 256, Y0 = blockIdx.y * 8;
  const float* __restrict__ xin = xall + (size_t)(b_ * 3 + c) * HW;

  for (int idx = tid; idx < RT * C; idx += 256) {
    const int r = idx / C, e = idx - r * C;
    int gy = Y0 - PM + r; gy = gy < 0 ? -gy : gy; gy = gy > 511 ? 1022 - gy : gy;
    int gx = X0 - ORI + e; gx = gx < 0 ? -gx : gx; gx = gx > 511 ? 1022 - gx : gx;
    tile[idx] = f2bf(xin[gy * 512 + gx]);
  }
  __syncthreads();
  convg_compute_store<I0, SB>(tid, b_, c, X0, Y0, tile, ot, wsb, out);
}

// ---------------- fp32 depthwise conv (blur 0 / full fallback) ----------------
template<int S>
__global__ __launch_bounds__(256) void conv_kernel(const float* __restrict__ xin_all,
                                                   const float* __restrict__ wg,
                                                   float* __restrict__ out, int ch0) {
  constexpr int P = (S - 1) / 2;
  constexpr int WHALO = 128 + 2 * P;
  constexpr int STRIDE = (WHALO + 3) & ~3;
  constexpr int HHALO = 32 + 2 * P;
  constexpr int NSEG = (S + 6) / 4;
  extern __shared__ float lds[];

  const int tx = threadIdx.x, ty = threadIdx.y;
  const int bz = blockIdx.z;
  const int b = bz / 3, c = bz - 3 * (bz / 3);
  const int x0 = blockIdx.x * 128, y0 = blockIdx.y * 32;
  const float* __restrict__ xin = xin_all + ((size_t)(b * 3 + c)) * HW;
  const float* __restrict__ wb = wg + c * (S * S);

  for (int ly = ty; ly < HHALO; ly += 8) {
    int gy = y0 - P + ly;
    gy = gy < 0 ? -gy : gy;
    gy = gy > 511 ? 1022 - gy : gy;
    const float* __restrict__ row = xin + (size_t)gy * 512;
    for (int lx = tx; lx < WHALO; lx += 32) {
      int gx = x0 - P + lx;
      gx = gx < 0 ? -gx : gx;
      gx = gx > 511 ? 1022 - gx : gx;
      lds[ly * STRIDE + lx] = row[gx];
    }
  }
  __syncthreads();

  float acc[4][4] = {};
  const int basecol = tx * 4;
  const int lrow0 = ty * 4;

#pragma unroll 1
  for (int ri = 0; ri < S + 3; ++ri) {
    float seg[NSEG * 4];
    const float* lp = &lds[(lrow0 + ri) * STRIDE + basecol];
#pragma unroll
    for (int j2 = 0; j2 < NSEG; ++j2) {
      const float4 v = *(const float4*)(lp + 4 * j2);
      seg[4 * j2 + 0] = v.x; seg[4 * j2 + 1] = v.y;
      seg[4 * j2 + 2] = v.z; seg[4 * j2 + 3] = v.w;
    }
#pragma unroll
    for (int r = 0; r < 4; ++r) {
      const int dy = ri - r;
      if (dy >= 0 && dy < S) {
        const float* __restrict__ wrow = wb + dy * S;
#pragma unroll
        for (int dx = 0; dx < S; ++dx) {
          const float wv = wrow[dx];
#pragma unroll
          for (int cc = 0; cc < 4; ++cc)
            acc[r][cc] = fmaf(wv, seg[dx + cc], acc[r][cc]);
        }
      }
    }
  }

  float* __restrict__ o = out + ((size_t)b * OUTC + (ch0 + c)) * HW
                        + (size_t)(y0 + lrow0) * 512 + (x0 + basecol);
#pragma unroll
  for (int r = 0; r < 4; ++r) {
    f32x4 v = (f32x4){acc[r][0], acc[r][1], acc[r][2], acc[r][3]};
    nt_store4(v, o + (size_t)r * 512);
  }
}

extern "C" void kernel_launch(void* const* d_in, const int* in_sizes, int n_in,
                              void* d_out, int out_size, void* d_ws, size_t ws_size,
                              hipStream_t stream) {
  (void)in_sizes; (void)n_in; (void)out_size;
  const float* x = (const float*)d_in[0];
  float* out = (float*)d_out;
  float* w = (float*)d_ws;

  KPtrs kp;
  for (int i = 0; i < NUMB; ++i) kp.k[i] = (const float*)d_in[1 + i];

  int offs[NUMB];
  { int off = 0; for (int i = 0; i < NUMB; ++i) { offs[i] = off; const int s = 3 + 2 * i; off += 3 * s * s; } }

#define LAUNCH_CONV(I) do { \
    constexpr int S_ = 3 + 2 * (I); \
    constexpr int P_ = (I) + 1; \
    constexpr int STRIDE_ = ((128 + 2 * P_) + 3) & ~3; \
    constexpr int HHALO_ = 32 + 2 * P_; \
    conv_kernel<S_><<<dim3(4, 16, 12), dim3(32, 8), (size_t)STRIDE_ * HHALO_ * sizeof(float), stream>>>( \
        x, w + offs[I], out, 3 + 3 * (I)); \
  } while (0)

  if (ws_size >= WS_NEEDED) {
    // 3-launch chain: prep1 (pad+weights) -> prep2 (blur0+packB) -> convg
    prep1_kernel<<<dim3(1911), dim3(256), 0, stream>>>(x, (uint4*)d_ws, out, kp, w);
    prep2_kernel<<<dim3(1545), dim3(256), 0, stream>>>(x, w, (uint4*)d_ws, out);
    const unsigned short* pimg = (const unsigned short*)((const uint4*)d_ws + PIMG_U4);
    convg_all_kernel<<<dim3(7680), dim3(256), 0, stream>>>(pimg, (const uint4*)d_ws, out);
  } else if (ws_size >= WS_MID) {
    weights_kernel<<<dim3(63), dim3(256), 0, stream>>>(kp, w);
    copy_x_kernel<<<dim3(3072), dim3(256), 0, stream>>>((const f32x4*)x, (f32x4*)out);
    LAUNCH_CONV(0);
    pack_b2_kernel<<<dim3(259, 4, 3), dim3(64), 0, stream>>>(w, (uint4*)d_ws);
    convg_kernel<17, 173><<<dim3(2, 64, 12), dim3(256), 0, stream>>>(x, (const uint4*)d_ws, out);
    convg_kernel<13, 103><<<dim3(2, 64, 12), dim3(256), 0, stream>>>(x, (const uint4*)d_ws, out);
    convg_kernel<9,  49 ><<<dim3(2, 64, 12), dim3(256), 0, stream>>>(x, (const uint4*)d_ws, out);
    convg_kernel<5,  11 ><<<dim3(2, 64, 12), dim3(256), 0, stream>>>(x, (const uint4*)d_ws, out);
    convg_kernel<1,  0  ><<<dim3(2, 64, 12), dim3(256), 0, stream>>>(x, (const uint4*)d_ws, out);
  } else {
    weights_kernel<<<dim3(63), dim3(256), 0, stream>>>(kp, w);
    copy_x_kernel<<<dim3(3072), dim3(256), 0, stream>>>((const f32x4*)x, (f32x4*)out);
    LAUNCH_CONV(0);
    LAUNCH_CONV(1);  LAUNCH_CONV(2);  LAUNCH_CONV(3);  LAUNCH_CONV(4);
    LAUNCH_CONV(5);  LAUNCH_CONV(6);  LAUNCH_CONV(7);  LAUNCH_CONV(8);
    LAUNCH_CONV(9);  LAUNCH_CONV(10); LAUNCH_CONV(11); LAUNCH_CONV(12);
    LAUNCH_CONV(13); LAUNCH_CONV(14); LAUNCH_CONV(15); LAUNCH_CONV(16);
    LAUNCH_CONV(17); LAUNCH_CONV(18); LAUNCH_CONV(19); LAUNCH_CONV(20);
  }
#undef LAUNCH_CONV
}

// Round 11
// 167.727 us; speedup vs baseline: 1.0422x; 1.0212x over previous
//
#include <hip/hip_runtime.h>
#include <cmath>

#define NUMB 21
#define HW (512*512)
#define OUTC 66   // 3*(NUM+1)

using short8 = __attribute__((ext_vector_type(8))) short;
using f32x4  = __attribute__((ext_vector_type(4))) float;

// ---- d_ws layout (uint4 units) ----
// [0, 12288)            fp32 weights (194568 B used)
// [12288, 211200)       packed B fragments (768*259 u4)
// [211200, 681600)      padded bf16 image 12 x 560 x 560
#define WSB4 12288u
#define PIMG_U4 211200u
#define WS_MID 3379200u        // bytes: weights + packed B
#define WS_NEEDED 10905600u    // bytes: + padded image

struct KPtrs { const float* k[NUMB]; };

__device__ __forceinline__ unsigned short f2bf(float f) {
  unsigned u = __builtin_bit_cast(unsigned, f);
  unsigned r = (u + 0x7fffu + ((u >> 16) & 1u)) >> 16;
  return (unsigned short)r;
}

__device__ __forceinline__ void nt_store4(const f32x4 v, float* p) {
  __builtin_nontemporal_store(v, (f32x4*)p);
}

// ---------------- device bodies shared by fused + standalone kernels ----------------

__device__ __forceinline__ void weights_body(const int bid, const int tid,
                                             const KPtrs& kp, float* __restrict__ w,
                                             float* red) {
  const int i = bid / 3, c = bid - 3 * (bid / 3);
  const int p = i + 1, s = 2 * p + 1, q = p + 1;
  int off = 0;
  for (int j = 0; j < i; ++j) { const int sj = 3 + 2 * j; off += 3 * sj * sj; }
  float* __restrict__ wd = w + off + c * s * s;
  const float* __restrict__ kc = kp.k[i] + c * q * q;
  const int n = s * s;

  float m = -1e30f;
  for (int idx = tid; idx < n; idx += 256) {
    const int my = idx / s, nx = idx - my * s;
    const int a = min(my, 2 * p - my), bq = min(nx, 2 * p - nx);
    m = fmaxf(m, kc[a * q + bq] + kc[bq * q + a]);
  }
  red[tid] = m; __syncthreads();
  for (int st = 128; st > 0; st >>= 1) {
    if (tid < st) red[tid] = fmaxf(red[tid], red[tid + st]);
    __syncthreads();
  }
  const float vmax = red[0];
  __syncthreads();

  float sum = 0.f;
  for (int idx = tid; idx < n; idx += 256) {
    const int my = idx / s, nx = idx - my * s;
    const int a = min(my, 2 * p - my), bq = min(nx, 2 * p - nx);
    sum += expf(kc[a * q + bq] + kc[bq * q + a] - vmax);
  }
  red[tid] = sum; __syncthreads();
  for (int st = 128; st > 0; st >>= 1) {
    if (tid < st) red[tid] += red[tid + st];
    __syncthreads();
  }
  const float inv = 1.f / red[0];

  for (int idx = tid; idx < n; idx += 256) {
    const int my = idx / s, nx = idx - my * s;
    const int a = min(my, 2 * p - my), bq = min(nx, 2 * p - nx);
    wd[idx] = expf(kc[a * q + bq] + kc[bq * q + a] - vmax) * inv;
  }
}

__device__ __forceinline__ void pad_copy_body(const int ch, const int chunk,
                                              const float* __restrict__ x,
                                              uint4* __restrict__ ws,
                                              float* __restrict__ out) {
  if (chunk >= 39200) return;
  const int pr = chunk / 70, pc8 = (chunk - pr * 70) * 8;
  int gy = pr - 24; gy = gy < 0 ? -gy : gy; gy = gy > 511 ? 1022 - gy : gy;
  const float* __restrict__ row = x + (size_t)ch * HW + (size_t)gy * 512;
  unsigned short hs[8];
  if (pc8 >= 24 && pc8 <= 528) {
    const f32x4 v0 = *(const f32x4*)(row + pc8 - 24);
    const f32x4 v1 = *(const f32x4*)(row + pc8 - 20);
    hs[0] = f2bf(v0.x); hs[1] = f2bf(v0.y); hs[2] = f2bf(v0.z); hs[3] = f2bf(v0.w);
    hs[4] = f2bf(v1.x); hs[5] = f2bf(v1.y); hs[6] = f2bf(v1.z); hs[7] = f2bf(v1.w);
    if (pr >= 24 && pr < 536) {   // interior row: emit identity channel copy
      const int b = ch / 3, c = ch - 3 * (ch / 3);
      float* o = out + ((size_t)(b * OUTC + c)) * HW + (size_t)(pr - 24) * 512 + (pc8 - 24);
      nt_store4(v0, o); nt_store4(v1, o + 4);
    }
  } else {
#pragma unroll
    for (int j = 0; j < 8; ++j) {
      int gx = pc8 + j - 24; gx = gx < 0 ? -gx : gx; gx = gx > 511 ? 1022 - gx : gx;
      hs[j] = f2bf(row[gx]);
    }
  }
  uint4 o;
  o.x = (unsigned)hs[0] | ((unsigned)hs[1] << 16);
  o.y = (unsigned)hs[2] | ((unsigned)hs[3] << 16);
  o.z = (unsigned)hs[4] | ((unsigned)hs[5] << 16);
  o.w = (unsigned)hs[6] | ((unsigned)hs[7] << 16);
  ws[(size_t)PIMG_U4 + (size_t)ch * 39200 + chunk] = o;
}

__device__ __forceinline__ void pack_b2_body(const int gs, const int d, const int c,
                                             const int lane, const float* __restrict__ w,
                                             uint4* __restrict__ ws) {
  int I0, CS, sb, ag;
  if (gs < 11)       { I0 = 1;  CS = 1; sb = 0;   ag = 3; }
  else if (gs < 49)  { I0 = 5;  CS = 2; sb = 11;  ag = 7; }
  else if (gs < 103) { I0 = 9;  CS = 2; sb = 49;  ag = 3; }
  else if (gs < 173) { I0 = 13; CS = 2; sb = 103; ag = 7; }
  else               { I0 = 17; CS = 2; sb = 173; ag = 3; }
  const int T = 2 * I0 + 9, PM = I0 + 4, STEPS = T * CS;
  const int ORI = PM + ag;
  const int q = gs - sb;
  const int t  = (CS == 2) ? (q >> 1) : q;
  const int cs = (CS == 2) ? (q & 1) : 0;
  const int n = lane & 15, g4 = lane >> 4;
  const int j = n >> 2, h = n & 3;
  const int i = I0 + j;                 // absolute blur index
  const int p = i + 1, s = 2 * i + 3;
  int off = 0;
  for (int jj2 = 0; jj2 < i; ++jj2) { const int sj = 3 + 2 * jj2; off += 3 * sj * sj; }
  const float* __restrict__ wk = w + off + c * s * s;
  const int ky = t - PM + p;
  unsigned short hs[8];
#pragma unroll
  for (int jj = 0; jj < 8; ++jj) {
    const int k = 32 * cs + 8 * g4 + jj;
    const int kx = k - ORI - 4 * h - d + p;
    float v = 0.f;
    if (ky >= 0 && ky < s && kx >= 0 && kx < s) v = wk[ky * s + kx];
    hs[jj] = f2bf(v);
  }
  uint4 o;
  o.x = (unsigned)hs[0] | ((unsigned)hs[1] << 16);
  o.y = (unsigned)hs[2] | ((unsigned)hs[3] << 16);
  o.z = (unsigned)hs[4] | ((unsigned)hs[5] << 16);
  o.w = (unsigned)hs[6] | ((unsigned)hs[7] << 16);
  ws[(size_t)WSB4 + 768u * (unsigned)sb + (size_t)(((c * 4 + d) * STEPS + q) * 64 + lane)] = o;
}

// conv3 (blur 0, S=3) body; lds must be >= 34*132 floats
__device__ __forceinline__ void conv3_body(const int tid, const int bx, const int by, const int bz,
                                           const float* __restrict__ xin_all,
                                           const float* __restrict__ wg,
                                           float* __restrict__ out, float* lds) {
  constexpr int S = 3, P = 1;
  constexpr int WHALO = 130, STRIDE = 132, HHALO = 34, NSEG = 2;
  const int tx = tid & 31, ty = tid >> 5;
  const int b = bz / 3, c = bz - 3 * (bz / 3);
  const int x0 = bx * 128, y0 = by * 32;
  const float* __restrict__ xin = xin_all + ((size_t)(b * 3 + c)) * HW;
  const float* __restrict__ wb = wg + c * (S * S);

  for (int ly = ty; ly < HHALO; ly += 8) {
    int gy = y0 - P + ly;
    gy = gy < 0 ? -gy : gy;
    gy = gy > 511 ? 1022 - gy : gy;
    const float* __restrict__ row = xin + (size_t)gy * 512;
    for (int lx = tx; lx < WHALO; lx += 32) {
      int gx = x0 - P + lx;
      gx = gx < 0 ? -gx : gx;
      gx = gx > 511 ? 1022 - gx : gx;
      lds[ly * STRIDE + lx] = row[gx];
    }
  }
  __syncthreads();

  float acc[4][4] = {};
  const int basecol = tx * 4;
  const int lrow0 = ty * 4;

#pragma unroll 1
  for (int ri = 0; ri < S + 3; ++ri) {
    float seg[NSEG * 4];
    const float* lp = &lds[(lrow0 + ri) * STRIDE + basecol];
#pragma unroll
    for (int j2 = 0; j2 < NSEG; ++j2) {
      const float4 v = *(const float4*)(lp + 4 * j2);
      seg[4 * j2 + 0] = v.x; seg[4 * j2 + 1] = v.y;
      seg[4 * j2 + 2] = v.z; seg[4 * j2 + 3] = v.w;
    }
#pragma unroll
    for (int r = 0; r < 4; ++r) {
      const int dy = ri - r;
      if (dy >= 0 && dy < S) {
        const float* __restrict__ wrow = wb + dy * S;
#pragma unroll
        for (int dx = 0; dx < S; ++dx) {
          const float wv = wrow[dx];
#pragma unroll
          for (int cc = 0; cc < 4; ++cc)
            acc[r][cc] = fmaf(wv, seg[dx + cc], acc[r][cc]);
        }
      }
    }
  }

  float* __restrict__ o = out + ((size_t)b * OUTC + (3 + c)) * HW
                        + (size_t)(y0 + lrow0) * 512 + (x0 + basecol);
#pragma unroll
  for (int r = 0; r < 4; ++r) {
    f32x4 v = (f32x4){acc[r][0], acc[r][1], acc[r][2], acc[r][3]};
    nt_store4(v, o + (size_t)r * 512);
  }
}

// ---------------- fused prep1: pad_copy (1848 blocks) + weights (63 blocks) ----------------
__global__ __launch_bounds__(256) void prep1_kernel(const float* __restrict__ x,
                                                    uint4* __restrict__ ws,
                                                    float* __restrict__ out,
                                                    KPtrs kp, float* __restrict__ w) {
  __shared__ float red[256];
  const int bid = blockIdx.x, tid = threadIdx.x;
  if (bid < 1848) {
    const int ch = bid / 154, cb = bid - ch * 154;
    pad_copy_body(ch, cb * 256 + tid, x, ws, out);
  } else {
    weights_body(bid - 1848, tid, kp, w, red);
  }
}

// ---------------- prep2: pack_b2 only (777 blocks x 4 pack-units) ----------------
__global__ __launch_bounds__(256) void prep2_kernel(const float* __restrict__ w,
                                                    uint4* __restrict__ ws) {
  const int u = blockIdx.x * 4 + (threadIdx.x >> 6);   // 3108 pack units
  const int lane = threadIdx.x & 63;
  const int gs = u % 259, t2 = u / 259;
  const int d = t2 & 3, c = t2 >> 2;
  pack_b2_body(gs, d, c, lane, w, ws);
}

// ---------------- standalone kernels (fallback paths) ----------------
__global__ __launch_bounds__(256) void weights_kernel(KPtrs kp, float* __restrict__ w) {
  __shared__ float red[256];
  weights_body(blockIdx.x, threadIdx.x, kp, w, red);
}

__global__ __launch_bounds__(64) void pack_b2_kernel(const float* __restrict__ w,
                                                     uint4* __restrict__ ws) {
  pack_b2_body(blockIdx.x, blockIdx.y, blockIdx.z, threadIdx.x, w, ws);
}

__global__ __launch_bounds__(256) void copy_x_kernel(const f32x4* __restrict__ x,
                                                     f32x4* __restrict__ out) {
  const int idx = blockIdx.x * 256 + threadIdx.x;
  const int per_b = 3 * HW / 4;
  const int b = idx / per_b, r = idx - b * per_b;
  __builtin_nontemporal_store(x[idx], &out[(size_t)b * (OUTC * HW / 4) + r]);
}

// ---------------- shared MFMA compute + split-store (round-8 epilogue) ----------------
template<int I0, int SB>
__device__ __forceinline__ void convg_compute_store(const int tid, const int b_, const int c,
    const int X0, const int Y0, const unsigned short* __restrict__ tile, float* __restrict__ ot,
    const uint4* __restrict__ wsb, float* __restrict__ out) {
  constexpr int T  = 2 * I0 + 9;
  constexpr int CS = (I0 == 1) ? 1 : 2;
  constexpr int C  = (CS == 1) ? 272 : 304;
  constexpr int CH0 = 3 + 3 * I0;
  constexpr int STEPS = T * CS;

  const int lane = tid & 63, d = tid >> 6;       // wave = pixel phase d 0..3
  const int m = lane & 15, g4 = lane >> 4;
  const int abase = 16 * m + 8 * g4;             // A element base
  const uint4* __restrict__ bl = wsb + (size_t)WSB4 + 768u * (unsigned)SB
                               + (size_t)((c * 4 + d) * STEPS) * 64 + lane;

  f32x4 acc[8];
#pragma unroll
  for (int yy = 0; yy < 8; ++yy) acc[yy] = (f32x4){0.f, 0.f, 0.f, 0.f};

  short8 awin[8][CS];
#pragma unroll
  for (int r = 0; r < 7; ++r)
#pragma unroll
    for (int cs2 = 0; cs2 < CS; ++cs2)
      awin[r][cs2] = *(const short8*)(tile + r * C + abase + 32 * cs2);

  short8 Bf[4][CS];                               // ring-4, prefetch distance 3
#pragma unroll
  for (int tt = 0; tt < 3; ++tt)
#pragma unroll
    for (int cs2 = 0; cs2 < CS; ++cs2)
      Bf[tt][cs2] = __builtin_bit_cast(short8, bl[(tt * CS + cs2) * 64]);

  // T5: favor compute-phase waves over staging-phase blocks on the same CU
  __builtin_amdgcn_s_setprio(1);
#pragma unroll
  for (int t = 0; t < T; ++t) {
#pragma unroll
    for (int cs2 = 0; cs2 < CS; ++cs2)
      awin[(t + 7) & 7][cs2] = *(const short8*)(tile + (t + 7) * C + abase + 32 * cs2);
    if (t + 3 < T) {
#pragma unroll
      for (int cs2 = 0; cs2 < CS; ++cs2)
        Bf[(t + 3) & 3][cs2] = __builtin_bit_cast(short8, bl[((t + 3) * CS + cs2) * 64]);
    }
#pragma unroll
    for (int yy = 0; yy < 8; ++yy)
#pragma unroll
      for (int cs2 = 0; cs2 < CS; ++cs2)
        acc[yy] = __builtin_amdgcn_mfma_f32_16x16x32_bf16(awin[(t + yy) & 7][cs2],
                                                          Bf[t & 3][cs2], acc[yy], 0, 0, 0);
  }
  __builtin_amdgcn_s_setprio(0);

  // ---- coalesced store via LDS transpose, two 4-row halves ----
  // Bank note: scatter write is d-pinned (bank%4 == d) -> 8-way floor. Reach it by
  // flipping r's bit per odd g4 (chunk ^= 4*(g4&1)); reader un-permutes on the
  // GLOBAL side (within-256B float4 shuffle, still coalesced), LDS reads stay linear.
  const int rx = g4 & 1;
#pragma unroll
  for (int H = 0; H < 2; ++H) {
    __syncthreads();                             // H=0: done reading tile; H=1: half-0 drained
    {
      const int n = lane & 15;
      const int j = n >> 2, h = n & 3;
#pragma unroll
      for (int q = 0; q < 4; ++q) {
        float* orow = ot + (q * 4 + j) * 260 + 64 * g4 + 4 * h + d;
        const int yy = H * 4 + q;
#pragma unroll
        for (int r = 0; r < 4; ++r) orow[16 * (r ^ rx)] = acc[yy][r];
      }
    }
    __syncthreads();
    {
      const int jw = tid >> 6, rem = tid & 63;
      const int yy2l = rem >> 4, xq2 = rem & 15;
      float* __restrict__ obase = out + ((size_t)(b_ * OUTC + CH0 + 3 * jw + c)) * HW
                                + (size_t)(Y0 + H * 4 + yy2l) * 512 + X0;
      const float* __restrict__ srow = ot + (yy2l * 4 + jw) * 260;
#pragma unroll
      for (int v = 0; v < 4; ++v) {
        const int lofs = v * 64 + 4 * xq2;                    // physical LDS chunk
        const int gofs = v * 64 + 4 * (xq2 ^ (4 * (v & 1))); // logical/global chunk
        nt_store4(*(const f32x4*)(srow + lofs), obase + gofs);
      }
    }
  }
}

// ---------------- merged MFMA conv: global_load_lds staging from padded bf16 image ----------------
template<int I0, int SB>
__device__ __forceinline__ void convg_body(const int lbid,
    const unsigned short* __restrict__ pimg, const uint4* __restrict__ wsb,
    float* __restrict__ out, char* smem) {
  constexpr int T  = 2 * I0 + 9;
  constexpr int CS = (I0 == 1) ? 1 : 2;
  constexpr int PM = I0 + 4;
  constexpr int AG = (8 - (PM & 7)) & 7;
  constexpr int ORI = PM + AG;
  constexpr int RT = T + 7;
  constexpr int C  = (CS == 1) ? 272 : 304;
  constexpr int CW8 = C / 8;
  constexpr int NIDX = RT * CW8;
  static_assert(NIDX * 16 <= 32768, "tile overflow");

  unsigned short* tile = (unsigned short*)smem;
  float* ot = (float*)smem;
  const int tid = threadIdx.x;
  const int bx = lbid & 1, by = (lbid >> 1) & 63, bz = lbid >> 7;
  const int b_ = bz / 3, c = bz - b_ * 3;
  const int X0 = bx * 256, Y0 = by * 8;

  const unsigned short* __restrict__ pb = pimg + (size_t)(b_ * 3 + c) * 313600
        + (size_t)(Y0 - PM + 24) * 560 + (X0 - ORI + 24);
  {
    const int wid = tid >> 6, lane = tid & 63;
    for (int base = wid * 64; base < NIDX; base += 256) {
      const int idx = base + lane;
      const int r = idx / CW8, cc = idx - r * CW8;
      const unsigned short* src = pb + r * 560 + cc * 8;
      unsigned short* dst = tile + (size_t)base * 8;   // wave-uniform; HW appends lane*16B
      if (idx < NIDX)
        __builtin_amdgcn_global_load_lds(
            (const __attribute__((address_space(1))) void*)src,
            (__attribute__((address_space(3))) void*)dst, 16, 0, 0);
    }
  }
  __syncthreads();
  convg_compute_store<I0, SB>(tid, b_, c, X0, Y0, tile, ot, wsb, out);
}

__global__ __launch_bounds__(256, 4) void convg_all_kernel(
    const float* __restrict__ x, const unsigned short* __restrict__ pimg,
    const uint4* __restrict__ wsb, const float* __restrict__ w,
    float* __restrict__ out) {
  __shared__ __align__(16) char smem[32768];
  const int gi = blockIdx.x;
  if (gi >= 7680) {           // tail-fill: blur-0 fp32 conv rides convg's tail
    const int bid = gi - 7680;
    conv3_body(threadIdx.x, bid & 3, (bid >> 2) & 15, bid >> 6, x, w, out, (float*)smem);
    return;
  }
  // group-local XCD swizzle: each XCD (gi%8) owns 192 contiguous lbids.
  const int grp = gi / 1536;
  const int lb = gi - grp * 1536;
  const int lbid = (lb & 7) * 192 + (lb >> 3);
  if (grp == 0)      convg_body<17, 173>(lbid, pimg, wsb, out, smem);
  else if (grp == 1) convg_body<13, 103>(lbid, pimg, wsb, out, smem);
  else if (grp == 2) convg_body<9,  49 >(lbid, pimg, wsb, out, smem);
  else if (grp == 3) convg_body<5,  11 >(lbid, pimg, wsb, out, smem);
  else               convg_body<1,  0  >(lbid, pimg, wsb, out, smem);
}

// ---------------- per-group MFMA conv, scalar staging (mid-ws fallback) ----------------
template<int I0, int SB>
__global__ __launch_bounds__(256, 3) void convg_kernel(const float* __restrict__ xall,
                                                       const uint4* __restrict__ wsb,
                                                       float* __restrict__ out) {
  constexpr int T  = 2 * I0 + 9;
  constexpr int PM = I0 + 4;
  constexpr int AG = (8 - (PM & 7)) & 7;
  constexpr int ORI = PM + AG;
  constexpr int RT = T + 7;
  constexpr int CS = (I0 == 1) ? 1 : 2;
  constexpr int C  = (CS == 1) ? 272 : 304;

  __shared__ __align__(16) char smem[32768];
  unsigned short* tile = (unsigned short*)smem;
  float* ot = (float*)smem;

  const int tid = threadIdx.x;
  const int b_ = blockIdx.z / 3, c = blockIdx.z - b_ * 3;
  const int X0 = blockIdx.x * 256, Y0 = blockIdx.y * 8;
  const float* __restrict__ xin = xall + (size_t)(b_ * 3 + c) * HW;

  for (int idx = tid; idx < RT * C; idx += 256) {
    const int r = idx / C, e = idx - r * C;
    int gy = Y0 - PM + r; gy = gy < 0 ? -gy : gy; gy = gy > 511 ? 1022 - gy : gy;
    int gx = X0 - ORI + e; gx = gx < 0 ? -gx : gx; gx = gx > 511 ? 1022 - gx : gx;
    tile[idx] = f2bf(xin[gy * 512 + gx]);
  }
  __syncthreads();
  convg_compute_store<I0, SB>(tid, b_, c, X0, Y0, tile, ot, wsb, out);
}

// ---------------- fp32 depthwise conv (blur 0 / full fallback) ----------------
template<int S>
__global__ __launch_bounds__(256) void conv_kernel(const float* __restrict__ xin_all,
                                                   const float* __restrict__ wg,
                                                   float* __restrict__ out, int ch0) {
  constexpr int P = (S - 1) / 2;
  constexpr int WHALO = 128 + 2 * P;
  constexpr int STRIDE = (WHALO + 3) & ~3;
  constexpr int HHALO = 32 + 2 * P;
  constexpr int NSEG = (S + 6) / 4;
  extern __shared__ float lds[];

  const int tx = threadIdx.x, ty = threadIdx.y;
  const int bz = blockIdx.z;
  const int b = bz / 3, c = bz - 3 * (bz / 3);
  const int x0 = blockIdx.x * 128, y0 = blockIdx.y * 32;
  const float* __restrict__ xin = xin_all + ((size_t)(b * 3 + c)) * HW;
  const float* __restrict__ wb = wg + c * (S * S);

  for (int ly = ty; ly < HHALO; ly += 8) {
    int gy = y0 - P + ly;
    gy = gy < 0 ? -gy : gy;
    gy = gy > 511 ? 1022 - gy : gy;
    const float* __restrict__ row = xin + (size_t)gy * 512;
    for (int lx = tx; lx < WHALO; lx += 32) {
      int gx = x0 - P + lx;
      gx = gx < 0 ? -gx : gx;
      gx = gx > 511 ? 1022 - gx : gx;
      lds[ly * STRIDE + lx] = row[gx];
    }
  }
  __syncthreads();

  float acc[4][4] = {};
  const int basecol = tx * 4;
  const int lrow0 = ty * 4;

#pragma unroll 1
  for (int ri = 0; ri < S + 3; ++ri) {
    float seg[NSEG * 4];
    const float* lp = &lds[(lrow0 + ri) * STRIDE + basecol];
#pragma unroll
    for (int j2 = 0; j2 < NSEG; ++j2) {
      const float4 v = *(const float4*)(lp + 4 * j2);
      seg[4 * j2 + 0] = v.x; seg[4 * j2 + 1] = v.y;
      seg[4 * j2 + 2] = v.z; seg[4 * j2 + 3] = v.w;
    }
#pragma unroll
    for (int r = 0; r < 4; ++r) {
      const int dy = ri - r;
      if (dy >= 0 && dy < S) {
        const float* __restrict__ wrow = wb + dy * S;
#pragma unroll
        for (int dx = 0; dx < S; ++dx) {
          const float wv = wrow[dx];
#pragma unroll
          for (int cc = 0; cc < 4; ++cc)
            acc[r][cc] = fmaf(wv, seg[dx + cc], acc[r][cc]);
        }
      }
    }
  }

  float* __restrict__ o = out + ((size_t)b * OUTC + (ch0 + c)) * HW
                        + (size_t)(y0 + lrow0) * 512 + (x0 + basecol);
#pragma unroll
  for (int r = 0; r < 4; ++r) {
    f32x4 v = (f32x4){acc[r][0], acc[r][1], acc[r][2], acc[r][3]};
    nt_store4(v, o + (size_t)r * 512);
  }
}

extern "C" void kernel_launch(void* const* d_in, const int* in_sizes, int n_in,
                              void* d_out, int out_size, void* d_ws, size_t ws_size,
                              hipStream_t stream) {
  (void)in_sizes; (void)n_in; (void)out_size;
  const float* x = (const float*)d_in[0];
  float* out = (float*)d_out;
  float* w = (float*)d_ws;

  KPtrs kp;
  for (int i = 0; i < NUMB; ++i) kp.k[i] = (const float*)d_in[1 + i];

  int offs[NUMB];
  { int off = 0; for (int i = 0; i < NUMB; ++i) { offs[i] = off; const int s = 3 + 2 * i; off += 3 * s * s; } }

#define LAUNCH_CONV(I) do { \
    constexpr int S_ = 3 + 2 * (I); \
    constexpr int P_ = (I) + 1; \
    constexpr int STRIDE_ = ((128 + 2 * P_) + 3) & ~3; \
    constexpr int HHALO_ = 32 + 2 * P_; \
    conv_kernel<S_><<<dim3(4, 16, 12), dim3(32, 8), (size_t)STRIDE_ * HHALO_ * sizeof(float), stream>>>( \
        x, w + offs[I], out, 3 + 3 * (I)); \
  } while (0)

  if (ws_size >= WS_NEEDED) {
    // 3-launch chain: prep1 (pad+weights) -> prep2 (packB) -> convg (+blur0 tail-fill)
    prep1_kernel<<<dim3(1911), dim3(256), 0, stream>>>(x, (uint4*)d_ws, out, kp, w);
    prep2_kernel<<<dim3(777), dim3(256), 0, stream>>>(w, (uint4*)d_ws);
    const unsigned short* pimg = (const unsigned short*)((const uint4*)d_ws + PIMG_U4);
    convg_all_kernel<<<dim3(8448), dim3(256), 0, stream>>>(x, pimg, (const uint4*)d_ws, w, out);
  } else if (ws_size >= WS_MID) {
    weights_kernel<<<dim3(63), dim3(256), 0, stream>>>(kp, w);
    copy_x_kernel<<<dim3(3072), dim3(256), 0, stream>>>((const f32x4*)x, (f32x4*)out);
    LAUNCH_CONV(0);
    pack_b2_kernel<<<dim3(259, 4, 3), dim3(64), 0, stream>>>(w, (uint4*)d_ws);
    convg_kernel<17, 173><<<dim3(2, 64, 12), dim3(256), 0, stream>>>(x, (const uint4*)d_ws, out);
    convg_kernel<13, 103><<<dim3(2, 64, 12), dim3(256), 0, stream>>>(x, (const uint4*)d_ws, out);
    convg_kernel<9,  49 ><<<dim3(2, 64, 12), dim3(256), 0, stream>>>(x, (const uint4*)d_ws, out);
    convg_kernel<5,  11 ><<<dim3(2, 64, 12), dim3(256), 0, stream>>>(x, (const uint4*)d_ws, out);
    convg_kernel<1,  0  ><<<dim3(2, 64, 12), dim3(256), 0, stream>>>(x, (const uint4*)d_ws, out);
  } else {
    weights_kernel<<<dim3(63), dim3(256), 0, stream>>>(kp, w);
    copy_x_kernel<<<dim3(3072), dim3(256), 0, stream>>>((const f32x4*)x, (f32x4*)out);
    LAUNCH_CONV(0);
    LAUNCH_CONV(1);  LAUNCH_CONV(2);  LAUNCH_CONV(3);  LAUNCH_CONV(4);
    LAUNCH_CONV(5);  LAUNCH_CONV(6);  LAUNCH_CONV(7);  LAUNCH_CONV(8);
    LAUNCH_CONV(9);  LAUNCH_CONV(10); LAUNCH_CONV(11); LAUNCH_CONV(12);
    LAUNCH_CONV(13); LAUNCH_CONV(14); LAUNCH_CONV(15); LAUNCH_CONV(16);
    LAUNCH_CONV(17); LAUNCH_CONV(18); LAUNCH_CONV(19); LAUNCH_CONV(20);
  }
#undef LAUNCH_CONV
}

// Round 12
// 167.451 us; speedup vs baseline: 1.0439x; 1.0017x over previous
//
#include <hip/hip_runtime.h>
#include <cmath>

#define NUMB 21
#define HW (512*512)
#define OUTC 66   // 3*(NUM+1)

using short8 = __attribute__((ext_vector_type(8))) short;
using f32x4  = __attribute__((ext_vector_type(4))) float;

// ---- d_ws layout (uint4 units) ----
// [0, 12288)            fp32 weights (194568 B used)
// [12288, 211200)       packed B fragments (768*259 u4)
// [211200, 681600)      padded bf16 image 12 x 560 x 560
#define WSB4 12288u
#define PIMG_U4 211200u
#define WS_MID 3379200u        // bytes: weights + packed B
#define WS_NEEDED 10905600u    // bytes: + padded image

struct KPtrs { const float* k[NUMB]; };

__device__ __forceinline__ unsigned short f2bf(float f) {
  unsigned u = __builtin_bit_cast(unsigned, f);
  unsigned r = (u + 0x7fffu + ((u >> 16) & 1u)) >> 16;
  return (unsigned short)r;
}

__device__ __forceinline__ void nt_store4(const f32x4 v, float* p) {
  __builtin_nontemporal_store(v, (f32x4*)p);
}

// ---------------- device bodies shared by fused + standalone kernels ----------------

__device__ __forceinline__ void weights_body(const int bid, const int tid,
                                             const KPtrs& kp, float* __restrict__ w,
                                             float* red) {
  const int i = bid / 3, c = bid - 3 * (bid / 3);
  const int p = i + 1, s = 2 * p + 1, q = p + 1;
  int off = 0;
  for (int j = 0; j < i; ++j) { const int sj = 3 + 2 * j; off += 3 * sj * sj; }
  float* __restrict__ wd = w + off + c * s * s;
  const float* __restrict__ kc = kp.k[i] + c * q * q;
  const int n = s * s;

  float m = -1e30f;
  for (int idx = tid; idx < n; idx += 256) {
    const int my = idx / s, nx = idx - my * s;
    const int a = min(my, 2 * p - my), bq = min(nx, 2 * p - nx);
    m = fmaxf(m, kc[a * q + bq] + kc[bq * q + a]);
  }
  red[tid] = m; __syncthreads();
  for (int st = 128; st > 0; st >>= 1) {
    if (tid < st) red[tid] = fmaxf(red[tid], red[tid + st]);
    __syncthreads();
  }
  const float vmax = red[0];
  __syncthreads();

  float sum = 0.f;
  for (int idx = tid; idx < n; idx += 256) {
    const int my = idx / s, nx = idx - my * s;
    const int a = min(my, 2 * p - my), bq = min(nx, 2 * p - nx);
    sum += expf(kc[a * q + bq] + kc[bq * q + a] - vmax);
  }
  red[tid] = sum; __syncthreads();
  for (int st = 128; st > 0; st >>= 1) {
    if (tid < st) red[tid] += red[tid + st];
    __syncthreads();
  }
  const float inv = 1.f / red[0];

  for (int idx = tid; idx < n; idx += 256) {
    const int my = idx / s, nx = idx - my * s;
    const int a = min(my, 2 * p - my), bq = min(nx, 2 * p - nx);
    wd[idx] = expf(kc[a * q + bq] + kc[bq * q + a] - vmax) * inv;
  }
}

__device__ __forceinline__ void pad_copy_body(const int ch, const int chunk,
                                              const float* __restrict__ x,
                                              uint4* __restrict__ ws,
                                              float* __restrict__ out) {
  if (chunk >= 39200) return;
  const int pr = chunk / 70, pc8 = (chunk - pr * 70) * 8;
  int gy = pr - 24; gy = gy < 0 ? -gy : gy; gy = gy > 511 ? 1022 - gy : gy;
  const float* __restrict__ row = x + (size_t)ch * HW + (size_t)gy * 512;
  unsigned short hs[8];
  if (pc8 >= 24 && pc8 <= 528) {
    const f32x4 v0 = *(const f32x4*)(row + pc8 - 24);
    const f32x4 v1 = *(const f32x4*)(row + pc8 - 20);
    hs[0] = f2bf(v0.x); hs[1] = f2bf(v0.y); hs[2] = f2bf(v0.z); hs[3] = f2bf(v0.w);
    hs[4] = f2bf(v1.x); hs[5] = f2bf(v1.y); hs[6] = f2bf(v1.z); hs[7] = f2bf(v1.w);
    if (pr >= 24 && pr < 536) {   // interior row: emit identity channel copy
      const int b = ch / 3, c = ch - 3 * (ch / 3);
      float* o = out + ((size_t)(b * OUTC + c)) * HW + (size_t)(pr - 24) * 512 + (pc8 - 24);
      nt_store4(v0, o); nt_store4(v1, o + 4);
    }
  } else {
#pragma unroll
    for (int j = 0; j < 8; ++j) {
      int gx = pc8 + j - 24; gx = gx < 0 ? -gx : gx; gx = gx > 511 ? 1022 - gx : gx;
      hs[j] = f2bf(row[gx]);
    }
  }
  uint4 o;
  o.x = (unsigned)hs[0] | ((unsigned)hs[1] << 16);
  o.y = (unsigned)hs[2] | ((unsigned)hs[3] << 16);
  o.z = (unsigned)hs[4] | ((unsigned)hs[5] << 16);
  o.w = (unsigned)hs[6] | ((unsigned)hs[7] << 16);
  ws[(size_t)PIMG_U4 + (size_t)ch * 39200 + chunk] = o;
}

__device__ __forceinline__ void pack_b2_body(const int gs, const int d, const int c,
                                             const int lane, const float* __restrict__ w,
                                             uint4* __restrict__ ws) {
  int I0, CS, sb, ag;
  if (gs < 11)       { I0 = 1;  CS = 1; sb = 0;   ag = 3; }
  else if (gs < 49)  { I0 = 5;  CS = 2; sb = 11;  ag = 7; }
  else if (gs < 103) { I0 = 9;  CS = 2; sb = 49;  ag = 3; }
  else if (gs < 173) { I0 = 13; CS = 2; sb = 103; ag = 7; }
  else               { I0 = 17; CS = 2; sb = 173; ag = 3; }
  const int T = 2 * I0 + 9, PM = I0 + 4, STEPS = T * CS;
  const int ORI = PM + ag;
  const int q = gs - sb;
  const int t  = (CS == 2) ? (q >> 1) : q;
  const int cs = (CS == 2) ? (q & 1) : 0;
  const int n = lane & 15, g4 = lane >> 4;
  const int j = n >> 2, h = n & 3;
  const int i = I0 + j;                 // absolute blur index
  const int p = i + 1, s = 2 * i + 3;
  int off = 0;
  for (int jj2 = 0; jj2 < i; ++jj2) { const int sj = 3 + 2 * jj2; off += 3 * sj * sj; }
  const float* __restrict__ wk = w + off + c * s * s;
  const int ky = t - PM + p;
  unsigned short hs[8];
#pragma unroll
  for (int jj = 0; jj < 8; ++jj) {
    const int k = 32 * cs + 8 * g4 + jj;
    const int kx = k - ORI - 4 * h - d + p;
    float v = 0.f;
    if (ky >= 0 && ky < s && kx >= 0 && kx < s) v = wk[ky * s + kx];
    hs[jj] = f2bf(v);
  }
  uint4 o;
  o.x = (unsigned)hs[0] | ((unsigned)hs[1] << 16);
  o.y = (unsigned)hs[2] | ((unsigned)hs[3] << 16);
  o.z = (unsigned)hs[4] | ((unsigned)hs[5] << 16);
  o.w = (unsigned)hs[6] | ((unsigned)hs[7] << 16);
  ws[(size_t)WSB4 + 768u * (unsigned)sb + (size_t)(((c * 4 + d) * STEPS + q) * 64 + lane)] = o;
}

// conv3 (blur 0, S=3) body; lds must be >= 34*132 floats
__device__ __forceinline__ void conv3_body(const int tid, const int bx, const int by, const int bz,
                                           const float* __restrict__ xin_all,
                                           const float* __restrict__ wg,
                                           float* __restrict__ out, float* lds) {
  constexpr int S = 3, P = 1;
  constexpr int WHALO = 130, STRIDE = 132, HHALO = 34, NSEG = 2;
  const int tx = tid & 31, ty = tid >> 5;
  const int b = bz / 3, c = bz - 3 * (bz / 3);
  const int x0 = bx * 128, y0 = by * 32;
  const float* __restrict__ xin = xin_all + ((size_t)(b * 3 + c)) * HW;
  const float* __restrict__ wb = wg + c * (S * S);

  for (int ly = ty; ly < HHALO; ly += 8) {
    int gy = y0 - P + ly;
    gy = gy < 0 ? -gy : gy;
    gy = gy > 511 ? 1022 - gy : gy;
    const float* __restrict__ row = xin + (size_t)gy * 512;
    for (int lx = tx; lx < WHALO; lx += 32) {
      int gx = x0 - P + lx;
      gx = gx < 0 ? -gx : gx;
      gx = gx > 511 ? 1022 - gx : gx;
      lds[ly * STRIDE + lx] = row[gx];
    }
  }
  __syncthreads();

  float acc[4][4] = {};
  const int basecol = tx * 4;
  const int lrow0 = ty * 4;

#pragma unroll 1
  for (int ri = 0; ri < S + 3; ++ri) {
    float seg[NSEG * 4];
    const float* lp = &lds[(lrow0 + ri) * STRIDE + basecol];
#pragma unroll
    for (int j2 = 0; j2 < NSEG; ++j2) {
      const float4 v = *(const float4*)(lp + 4 * j2);
      seg[4 * j2 + 0] = v.x; seg[4 * j2 + 1] = v.y;
      seg[4 * j2 + 2] = v.z; seg[4 * j2 + 3] = v.w;
    }
#pragma unroll
    for (int r = 0; r < 4; ++r) {
      const int dy = ri - r;
      if (dy >= 0 && dy < S) {
        const float* __restrict__ wrow = wb + dy * S;
#pragma unroll
        for (int dx = 0; dx < S; ++dx) {
          const float wv = wrow[dx];
#pragma unroll
          for (int cc = 0; cc < 4; ++cc)
            acc[r][cc] = fmaf(wv, seg[dx + cc], acc[r][cc]);
        }
      }
    }
  }

  float* __restrict__ o = out + ((size_t)b * OUTC + (3 + c)) * HW
                        + (size_t)(y0 + lrow0) * 512 + (x0 + basecol);
#pragma unroll
  for (int r = 0; r < 4; ++r) {
    f32x4 v = (f32x4){acc[r][0], acc[r][1], acc[r][2], acc[r][3]};
    nt_store4(v, o + (size_t)r * 512);
  }
}

// ---------------- fused prep1: pad_copy (1848 blocks) + weights (63 blocks) ----------------
__global__ __launch_bounds__(256) void prep1_kernel(const float* __restrict__ x,
                                                    uint4* __restrict__ ws,
                                                    float* __restrict__ out,
                                                    KPtrs kp, float* __restrict__ w) {
  __shared__ float red[256];
  const int bid = blockIdx.x, tid = threadIdx.x;
  if (bid < 1848) {
    const int ch = bid / 154, cb = bid - ch * 154;
    pad_copy_body(ch, cb * 256 + tid, x, ws, out);
  } else {
    weights_body(bid - 1848, tid, kp, w, red);
  }
}

// ---------------- prep2: pack_b2 only (777 blocks x 4 pack-units) ----------------
__global__ __launch_bounds__(256) void prep2_kernel(const float* __restrict__ w,
                                                    uint4* __restrict__ ws) {
  const int u = blockIdx.x * 4 + (threadIdx.x >> 6);   // 3108 pack units
  const int lane = threadIdx.x & 63;
  const int gs = u % 259, t2 = u / 259;
  const int d = t2 & 3, c = t2 >> 2;
  pack_b2_body(gs, d, c, lane, w, ws);
}

// ---------------- standalone kernels (fallback paths) ----------------
__global__ __launch_bounds__(256) void weights_kernel(KPtrs kp, float* __restrict__ w) {
  __shared__ float red[256];
  weights_body(blockIdx.x, threadIdx.x, kp, w, red);
}

__global__ __launch_bounds__(64) void pack_b2_kernel(const float* __restrict__ w,
                                                     uint4* __restrict__ ws) {
  pack_b2_body(blockIdx.x, blockIdx.y, blockIdx.z, threadIdx.x, w, ws);
}

__global__ __launch_bounds__(256) void copy_x_kernel(const f32x4* __restrict__ x,
                                                     f32x4* __restrict__ out) {
  const int idx = blockIdx.x * 256 + threadIdx.x;
  const int per_b = 3 * HW / 4;
  const int b = idx / per_b, r = idx - b * per_b;
  __builtin_nontemporal_store(x[idx], &out[(size_t)b * (OUTC * HW / 4) + r]);
}

// ---------------- shared MFMA compute + split-store (round-8 epilogue) ----------------
// Bf ring pre-initialized by caller BEFORE the staging barrier (L2 latency hidden
// under the syncthreads vmcnt(0) drain -- compiler cannot hoist loads across it).
template<int I0, int SB>
__device__ __forceinline__ void convg_compute_store(const int tid, const int b_, const int c,
    const int X0, const int Y0, const unsigned short* __restrict__ tile, float* __restrict__ ot,
    const uint4* __restrict__ bl, short8 (&Bf)[4][(I0 == 1) ? 1 : 2],
    float* __restrict__ out) {
  constexpr int T  = 2 * I0 + 9;
  constexpr int CS = (I0 == 1) ? 1 : 2;
  constexpr int C  = (CS == 1) ? 272 : 304;
  constexpr int CH0 = 3 + 3 * I0;

  const int lane = tid & 63, d = tid >> 6;       // wave = pixel phase d 0..3
  const int m = lane & 15, g4 = lane >> 4;
  const int abase = 16 * m + 8 * g4;             // A element base

  f32x4 acc[8];
#pragma unroll
  for (int yy = 0; yy < 8; ++yy) acc[yy] = (f32x4){0.f, 0.f, 0.f, 0.f};

  short8 awin[8][CS];
#pragma unroll
  for (int r = 0; r < 7; ++r)
#pragma unroll
    for (int cs2 = 0; cs2 < CS; ++cs2)
      awin[r][cs2] = *(const short8*)(tile + r * C + abase + 32 * cs2);

  // T5: favor compute-phase waves over staging-phase blocks on the same CU
  __builtin_amdgcn_s_setprio(1);
#pragma unroll
  for (int t = 0; t < T; ++t) {
#pragma unroll
    for (int cs2 = 0; cs2 < CS; ++cs2)
      awin[(t + 7) & 7][cs2] = *(const short8*)(tile + (t + 7) * C + abase + 32 * cs2);
    if (t + 3 < T) {
#pragma unroll
      for (int cs2 = 0; cs2 < CS; ++cs2)
        Bf[(t + 3) & 3][cs2] = __builtin_bit_cast(short8, bl[((t + 3) * CS + cs2) * 64]);
    }
#pragma unroll
    for (int yy = 0; yy < 8; ++yy)
#pragma unroll
      for (int cs2 = 0; cs2 < CS; ++cs2)
        acc[yy] = __builtin_amdgcn_mfma_f32_16x16x32_bf16(awin[(t + yy) & 7][cs2],
                                                          Bf[t & 3][cs2], acc[yy], 0, 0, 0);
  }
  __builtin_amdgcn_s_setprio(0);

  // ---- coalesced store via LDS transpose, two 4-row halves ----
  // Bank note: scatter write is d-pinned (bank%4 == d) -> 8-way floor. Reach it by
  // flipping r's bit per odd g4 (chunk ^= 4*(g4&1)); reader un-permutes on the
  // GLOBAL side (within-256B float4 shuffle, still coalesced), LDS reads stay linear.
  const int rx = g4 & 1;
#pragma unroll
  for (int H = 0; H < 2; ++H) {
    __syncthreads();                             // H=0: done reading tile; H=1: half-0 drained
    {
      const int n = lane & 15;
      const int j = n >> 2, h = n & 3;
#pragma unroll
      for (int q = 0; q < 4; ++q) {
        float* orow = ot + (q * 4 + j) * 260 + 64 * g4 + 4 * h + d;
        const int yy = H * 4 + q;
#pragma unroll
        for (int r = 0; r < 4; ++r) orow[16 * (r ^ rx)] = acc[yy][r];
      }
    }
    __syncthreads();
    {
      const int jw = tid >> 6, rem = tid & 63;
      const int yy2l = rem >> 4, xq2 = rem & 15;
      float* __restrict__ obase = out + ((size_t)(b_ * OUTC + CH0 + 3 * jw + c)) * HW
                                + (size_t)(Y0 + H * 4 + yy2l) * 512 + X0;
      const float* __restrict__ srow = ot + (yy2l * 4 + jw) * 260;
#pragma unroll
      for (int v = 0; v < 4; ++v) {
        const int lofs = v * 64 + 4 * xq2;                    // physical LDS chunk
        const int gofs = v * 64 + 4 * (xq2 ^ (4 * (v & 1))); // logical/global chunk
        nt_store4(*(const f32x4*)(srow + lofs), obase + gofs);
      }
    }
  }
}

// ---------------- merged MFMA conv: global_load_lds staging from padded bf16 image ----------------
template<int I0, int SB>
__device__ __forceinline__ void convg_body(const int lbid,
    const unsigned short* __restrict__ pimg, const uint4* __restrict__ wsb,
    float* __restrict__ out, char* smem) {
  constexpr int T  = 2 * I0 + 9;
  constexpr int CS = (I0 == 1) ? 1 : 2;
  constexpr int PM = I0 + 4;
  constexpr int AG = (8 - (PM & 7)) & 7;
  constexpr int ORI = PM + AG;
  constexpr int RT = T + 7;
  constexpr int C  = (CS == 1) ? 272 : 304;
  constexpr int CW8 = C / 8;
  constexpr int NIDX = RT * CW8;
  constexpr int STEPS = T * CS;
  static_assert(NIDX * 16 <= 32768, "tile overflow");

  unsigned short* tile = (unsigned short*)smem;
  float* ot = (float*)smem;
  const int tid = threadIdx.x;
  const int bx = lbid & 1, by = (lbid >> 1) & 63, bz = lbid >> 7;
  const int b_ = bz / 3, c = bz - b_ * 3;
  const int X0 = bx * 256, Y0 = by * 8;

  // ---- B-ring init issued BEFORE staging: latency hides under the barrier drain ----
  const int lane = tid & 63, wid = tid >> 6;
  const uint4* __restrict__ bl = wsb + (size_t)WSB4 + 768u * (unsigned)SB
                               + (size_t)((c * 4 + wid) * STEPS) * 64 + lane;
  short8 Bf[4][CS];
#pragma unroll
  for (int tt = 0; tt < 3; ++tt)
#pragma unroll
    for (int cs2 = 0; cs2 < CS; ++cs2)
      Bf[tt][cs2] = __builtin_bit_cast(short8, bl[(tt * CS + cs2) * 64]);

  const unsigned short* __restrict__ pb = pimg + (size_t)(b_ * 3 + c) * 313600
        + (size_t)(Y0 - PM + 24) * 560 + (X0 - ORI + 24);
  {
    for (int base = wid * 64; base < NIDX; base += 256) {
      const int idx = base + lane;
      const int r = idx / CW8, cc = idx - r * CW8;
      const unsigned short* src = pb + r * 560 + cc * 8;
      unsigned short* dst = tile + (size_t)base * 8;   // wave-uniform; HW appends lane*16B
      if (idx < NIDX)
        __builtin_amdgcn_global_load_lds(
            (const __attribute__((address_space(1))) void*)src,
            (__attribute__((address_space(3))) void*)dst, 16, 0, 0);
    }
  }
  __syncthreads();
  convg_compute_store<I0, SB>(tid, b_, c, X0, Y0, tile, ot, bl, Bf, out);
}

__global__ __launch_bounds__(256, 4) void convg_all_kernel(
    const float* __restrict__ x, const unsigned short* __restrict__ pimg,
    const uint4* __restrict__ wsb, const float* __restrict__ w,
    float* __restrict__ out) {
  __shared__ __align__(16) char smem[32768];
  const int gi = blockIdx.x;
  if (gi >= 7680) {           // tail-fill: blur-0 fp32 conv rides convg's tail
    const int bid = gi - 7680;
    conv3_body(threadIdx.x, bid & 3, (bid >> 2) & 15, bid >> 6, x, w, out, (float*)smem);
    return;
  }
  // group-local XCD swizzle: each XCD (gi%8) owns 192 contiguous lbids.
  const int grp = gi / 1536;
  const int lb = gi - grp * 1536;
  const int lbid = (lb & 7) * 192 + (lb >> 3);
  if (grp == 0)      convg_body<17, 173>(lbid, pimg, wsb, out, smem);
  else if (grp == 1) convg_body<13, 103>(lbid, pimg, wsb, out, smem);
  else if (grp == 2) convg_body<9,  49 >(lbid, pimg, wsb, out, smem);
  else if (grp == 3) convg_body<5,  11 >(lbid, pimg, wsb, out, smem);
  else               convg_body<1,  0  >(lbid, pimg, wsb, out, smem);
}

// ---------------- per-group MFMA conv, scalar staging (mid-ws fallback) ----------------
template<int I0, int SB>
__global__ __launch_bounds__(256, 3) void convg_kernel(const float* __restrict__ xall,
                                                       const uint4* __restrict__ wsb,
                                                       float* __restrict__ out) {
  constexpr int T  = 2 * I0 + 9;
  constexpr int PM = I0 + 4;
  constexpr int AG = (8 - (PM & 7)) & 7;
  constexpr int ORI = PM + AG;
  constexpr int RT = T + 7;
  constexpr int CS = (I0 == 1) ? 1 : 2;
  constexpr int C  = (CS == 1) ? 272 : 304;
  constexpr int STEPS = T * CS;

  __shared__ __align__(16) char smem[32768];
  unsigned short* tile = (unsigned short*)smem;
  float* ot = (float*)smem;

  const int tid = threadIdx.x;
  const int b_ = blockIdx.z / 3, c = blockIdx.z - b_ * 3;
  const int X0 = blockIdx.x * 256, Y0 = blockIdx.y * 8;
  const float* __restrict__ xin = xall + (size_t)(b_ * 3 + c) * HW;

  const int lane = tid & 63, wid = tid >> 6;
  const uint4* __restrict__ bl = (const uint4*)wsb + (size_t)WSB4 * 0   // keep type
                               ;
  const uint4* __restrict__ bl2 = wsb + (size_t)WSB4 + 768u * (unsigned)SB
                                + (size_t)((c * 4 + wid) * STEPS) * 64 + lane;
  (void)bl;
  short8 Bf[4][CS];
#pragma unroll
  for (int tt = 0; tt < 3; ++tt)
#pragma unroll
    for (int cs2 = 0; cs2 < CS; ++cs2)
      Bf[tt][cs2] = __builtin_bit_cast(short8, bl2[(tt * CS + cs2) * 64]);

  for (int idx = tid; idx < RT * C; idx += 256) {
    const int r = idx / C, e = idx - r * C;
    int gy = Y0 - PM + r; gy = gy < 0 ? -gy : gy; gy = gy > 511 ? 1022 - gy : gy;
    int gx = X0 - ORI + e; gx = gx < 0 ? -gx : gx; gx = gx > 511 ? 1022 - gx : gx;
    tile[idx] = f2bf(xin[gy * 512 + gx]);
  }
  __syncthreads();
  convg_compute_store<I0, SB>(tid, b_, c, X0, Y0, tile, ot, bl2, Bf, out);
}

// ---------------- fp32 depthwise conv (blur 0 / full fallback) ----------------
template<int S>
__global__ __launch_bounds__(256) void conv_kernel(const float* __restrict__ xin_all,
                                                   const float* __restrict__ wg,
                                                   float* __restrict__ out, int ch0) {
  constexpr int P = (S - 1) / 2;
  constexpr int WHALO = 128 + 2 * P;
  constexpr int STRIDE = (WHALO + 3) & ~3;
  constexpr int HHALO = 32 + 2 * P;
  constexpr int NSEG = (S + 6) / 4;
  extern __shared__ float lds[];

  const int tx = threadIdx.x, ty = threadIdx.y;
  const int bz = blockIdx.z;
  const int b = bz / 3, c = bz - 3 * (bz / 3);
  const int x0 = blockIdx.x * 128, y0 = blockIdx.y * 32;
  const float* __restrict__ xin = xin_all + ((size_t)(b * 3 + c)) * HW;
  const float* __restrict__ wb = wg + c * (S * S);

  for (int ly = ty; ly < HHALO; ly += 8) {
    int gy = y0 - P + ly;
    gy = gy < 0 ? -gy : gy;
    gy = gy > 511 ? 1022 - gy : gy;
    const float* __restrict__ row = xin + (size_t)gy * 512;
    for (int lx = tx; lx < WHALO; lx += 32) {
      int gx = x0 - P + lx;
      gx = gx < 0 ? -gx : gx;
      gx = gx > 511 ? 1022 - gx : gx;
      lds[ly * STRIDE + lx] = row[gx];
    }
  }
  __syncthreads();

  float acc[4][4] = {};
  const int basecol = tx * 4;
  const int lrow0 = ty * 4;

#pragma unroll 1
  for (int ri = 0; ri < S + 3; ++ri) {
    float seg[NSEG * 4];
    const float* lp = &lds[(lrow0 + ri) * STRIDE + basecol];
#pragma unroll
    for (int j2 = 0; j2 < NSEG; ++j2) {
      const float4 v = *(const float4*)(lp + 4 * j2);
      seg[4 * j2 + 0] = v.x; seg[4 * j2 + 1] = v.y;
      seg[4 * j2 + 2] = v.z; seg[4 * j2 + 3] = v.w;
    }
#pragma unroll
    for (int r = 0; r < 4; ++r) {
      const int dy = ri - r;
      if (dy >= 0 && dy < S) {
        const float* __restrict__ wrow = wb + dy * S;
#pragma unroll
        for (int dx = 0; dx < S; ++dx) {
          const float wv = wrow[dx];
#pragma unroll
          for (int cc = 0; cc < 4; ++cc)
            acc[r][cc] = fmaf(wv, seg[dx + cc], acc[r][cc]);
        }
      }
    }
  }

  float* __restrict__ o = out + ((size_t)b * OUTC + (ch0 + c)) * HW
                        + (size_t)(y0 + lrow0) * 512 + (x0 + basecol);
#pragma unroll
  for (int r = 0; r < 4; ++r) {
    f32x4 v = (f32x4){acc[r][0], acc[r][1], acc[r][2], acc[r][3]};
    nt_store4(v, o + (size_t)r * 512);
  }
}

extern "C" void kernel_launch(void* const* d_in, const int* in_sizes, int n_in,
                              void* d_out, int out_size, void* d_ws, size_t ws_size,
                              hipStream_t stream) {
  (void)in_sizes; (void)n_in; (void)out_size;
  const float* x = (const float*)d_in[0];
  float* out = (float*)d_out;
  float* w = (float*)d_ws;

  KPtrs kp;
  for (int i = 0; i < NUMB; ++i) kp.k[i] = (const float*)d_in[1 + i];

  int offs[NUMB];
  { int off = 0; for (int i = 0; i < NUMB; ++i) { offs[i] = off; const int s = 3 + 2 * i; off += 3 * s * s; } }

#define LAUNCH_CONV(I) do { \
    constexpr int S_ = 3 + 2 * (I); \
    constexpr int P_ = (I) + 1; \
    constexpr int STRIDE_ = ((128 + 2 * P_) + 3) & ~3; \
    constexpr int HHALO_ = 32 + 2 * P_; \
    conv_kernel<S_><<<dim3(4, 16, 12), dim3(32, 8), (size_t)STRIDE_ * HHALO_ * sizeof(float), stream>>>( \
        x, w + offs[I], out, 3 + 3 * (I)); \
  } while (0)

  if (ws_size >= WS_NEEDED) {
    // 3-launch chain: prep1 (pad+weights) -> prep2 (packB) -> convg (+blur0 tail-fill)
    prep1_kernel<<<dim3(1911), dim3(256), 0, stream>>>(x, (uint4*)d_ws, out, kp, w);
    prep2_kernel<<<dim3(777), dim3(256), 0, stream>>>(w, (uint4*)d_ws);
    const unsigned short* pimg = (const unsigned short*)((const uint4*)d_ws + PIMG_U4);
    convg_all_kernel<<<dim3(8448), dim3(256), 0, stream>>>(x, pimg, (const uint4*)d_ws, w, out);
  } else if (ws_size >= WS_MID) {
    weights_kernel<<<dim3(63), dim3(256), 0, stream>>>(kp, w);
    copy_x_kernel<<<dim3(3072), dim3(256), 0, stream>>>((const f32x4*)x, (f32x4*)out);
    LAUNCH_CONV(0);
    pack_b2_kernel<<<dim3(259, 4, 3), dim3(64), 0, stream>>>(w, (uint4*)d_ws);
    convg_kernel<17, 173><<<dim3(2, 64, 12), dim3(256), 0, stream>>>(x, (const uint4*)d_ws, out);
    convg_kernel<13, 103><<<dim3(2, 64, 12), dim3(256), 0, stream>>>(x, (const uint4*)d_ws, out);
    convg_kernel<9,  49 ><<<dim3(2, 64, 12), dim3(256), 0, stream>>>(x, (const uint4*)d_ws, out);
    convg_kernel<5,  11 ><<<dim3(2, 64, 12), dim3(256), 0, stream>>>(x, (const uint4*)d_ws, out);
    convg_kernel<1,  0  ><<<dim3(2, 64, 12), dim3(256), 0, stream>>>(x, (const uint4*)d_ws, out);
  } else {
    weights_kernel<<<dim3(63), dim3(256), 0, stream>>>(kp, w);
    copy_x_kernel<<<dim3(3072), dim3(256), 0, stream>>>((const f32x4*)x, (f32x4*)out);
    LAUNCH_CONV(0);
    LAUNCH_CONV(1);  LAUNCH_CONV(2);  LAUNCH_CONV(3);  LAUNCH_CONV(4);
    LAUNCH_CONV(5);  LAUNCH_CONV(6);  LAUNCH_CONV(7);  LAUNCH_CONV(8);
    LAUNCH_CONV(9);  LAUNCH_CONV(10); LAUNCH_CONV(11); LAUNCH_CONV(12);
    LAUNCH_CONV(13); LAUNCH_CONV(14); LAUNCH_CONV(15); LAUNCH_CONV(16);
    LAUNCH_CONV(17); LAUNCH_CONV(18); LAUNCH_CONV(19); LAUNCH_CONV(20);
  }
#undef LAUNCH_CONV
}